// Round 9
// baseline (1407.234 us; speedup 1.0000x reference)
//
#include <hip/hip_runtime.h>
#include <hip/hip_bf16.h>
#include <cstdint>
#include <cstddef>

#define N_NODES 20000
#define N_EDGES 640000
#define HID     128
#define OUT_DIM 64
#define NSTEPS  16
#define HSTEP   0.1f

typedef unsigned short u16;
typedef __attribute__((ext_vector_type(8))) short short8;   // 8 bf16 (4 VGPRs)
typedef __attribute__((ext_vector_type(4))) float f32x4;    // MFMA C/D

__device__ __forceinline__ float bf2f(u16 u) {
    union { unsigned int i; float f; } v; v.i = ((unsigned int)u) << 16; return v.f;
}
__device__ __forceinline__ u16 f2bf(float f) {
    union { float f; unsigned int i; } v; v.f = f;
    unsigned int x = v.i;
    unsigned int r = x + 0x7FFFu + ((x >> 16) & 1u);   // round-to-nearest-even
    return (u16)(r >> 16);
}

__device__ __forceinline__ float sigm(float x) { return 1.f / (1.f + __expf(-x)); }
__device__ __forceinline__ float tanh_fast(float x) {
    float e2 = __expf(-2.f * fabsf(x));
    float t = (1.f - e2) / (1.f + e2);
    return copysignf(t, x);
}

// ---------------------------------------------------------------------------
// Storage-dtype detection. flag=1 -> tensors stored as f32; flag=0 -> bf16.
// ---------------------------------------------------------------------------
__global__ void detect_kernel(const u16* __restrict__ xraw, int* __restrict__ flag) {
    __shared__ int cnt;
    if (threadIdx.x == 0) cnt = 0;
    __syncthreads();
    int c = 0;
    for (int i = threadIdx.x; i < 4096; i += 256) {
        int e = (xraw[i] >> 7) & 0xFF;
        if (e >= 0x90) c++;
    }
    atomicAdd(&cnt, c);
    __syncthreads();
    if (threadIdx.x == 0) *flag = (cnt > 100) ? 1 : 0;
}

// ---------------------------------------------------------------------------
// Packed conversion of the 15 weight/bias tensors into contiguous f32 ws.
// ---------------------------------------------------------------------------
#define N_CVT 15
struct CvtArgs { const void* s[N_CVT]; };
__constant__ const int cvt_off[N_CVT + 1] = {
    0, 16384, 16512, 32896, 33024, 98560, 164096, 164608, 165120,
    230656, 231168, 231680, 264448, 264576, 272768, 272832 };

__global__ void convert_kernel(CvtArgs a, float* __restrict__ dst,
                               const int* __restrict__ flag) {
    int i = blockIdx.x * blockDim.x + threadIdx.x;
    if (i >= 272832) return;
    int seg = 0;
    #pragma unroll
    for (int s = 1; s < N_CVT; ++s) if (i >= cvt_off[s]) seg = s;
    int j = i - cvt_off[seg];
    float v = (*flag) ? ((const float*)a.s[seg])[j]
                      : bf2f(((const u16*)a.s[seg])[j]);
    dst[i] = v;
}

// ---------------------------------------------------------------------------
// Build bf16 weights in MFMA B-fragment-swizzled order.
// elem (nt, ck, lane, j) = W[nt*16 + (lane&15)][ck*32 + (lane>>4)*8 + j]
// flat o = ((nt*NCK + ck)*64 + lane)*8 + j.
// WswzF: [Wihf|Whhf] KK=256 (131072); WswzB: Wihb KK=128 (65536);
// WswzH: Wf1 [128][256] KK=256 nt<8 (32768).
// ---------------------------------------------------------------------------
__global__ void build_wswz_kernel(const float* __restrict__ wsf,
                                  u16* __restrict__ WswzF, u16* __restrict__ WswzB,
                                  u16* __restrict__ WswzH) {
    int o = blockIdx.x * blockDim.x + threadIdx.x;
    if (o < 131072) {   // forward, NCK=8
        int j = o & 7, l = (o >> 3) & 63, rest = o >> 9;
        int ck = rest & 7, nt = rest >> 3;
        int n = nt * 16 + (l & 15);
        int k = ck * 32 + (l >> 4) * 8 + j;
        const float* Wihf = wsf + 33024;
        const float* Whhf = wsf + 98560;
        float v = (k < 128) ? Wihf[n * 128 + k] : Whhf[n * 128 + (k - 128)];
        WswzF[o] = f2bf(v);
    }
    if (o < 65536) {    // backward, NCK=4
        int j = o & 7, l = (o >> 3) & 63, rest = o >> 9;
        int ck = rest & 3, nt = rest >> 2;
        int n = nt * 16 + (l & 15);
        int k = ck * 32 + (l >> 4) * 8 + j;
        const float* Wihb = wsf + 165120;
        WswzB[o] = f2bf(Wihb[n * 128 + k]);
    }
    if (o < 32768) {    // fc1, NCK=8, nt<8
        int j = o & 7, l = (o >> 3) & 63, rest = o >> 9;
        int ck = rest & 7, nt = rest >> 3;
        int n = nt * 16 + (l & 15);
        int k = ck * 32 + (l >> 4) * 8 + j;
        const float* Wf1 = wsf + 231680;
        WswzH[o] = f2bf(Wf1[n * 256 + k]);
    }
}

// ---------------------------------------------------------------------------
// CSR build: degree count -> exclusive scan -> bucket fill
// ---------------------------------------------------------------------------
__global__ void count_kernel(const int* __restrict__ ei, int* __restrict__ deg) {
    int e = blockIdx.x * blockDim.x + threadIdx.x;
    if (e < N_EDGES) atomicAdd(&deg[ei[N_EDGES + e]], 1);
}

__global__ __launch_bounds__(1024) void scan_kernel(const int* __restrict__ deg,
                                                    int* __restrict__ rowptr,
                                                    float* __restrict__ degf) {
    __shared__ int sd[1024];
    const int t = threadIdx.x;
    const int CH = (N_NODES + 1023) / 1024;   // 20
    int base = t * CH;
    int s = 0;
    for (int i = 0; i < CH; ++i) {
        int idx = base + i;
        if (idx < N_NODES) s += deg[idx];
    }
    sd[t] = s;
    __syncthreads();
    for (int off = 1; off < 1024; off <<= 1) {
        int v = (t >= off) ? sd[t - off] : 0;
        __syncthreads();
        sd[t] += v;
        __syncthreads();
    }
    int run = (t == 0) ? 0 : sd[t - 1];
    for (int i = 0; i < CH; ++i) {
        int idx = base + i;
        if (idx < N_NODES) {
            rowptr[idx] = run;
            degf[idx] = (float)deg[idx];
            run += deg[idx];
        }
    }
    if (t == 1023) rowptr[N_NODES] = sd[1023];
}

__global__ void fill_kernel(const int* __restrict__ ei, const int* __restrict__ rowptr,
                            int* __restrict__ fill, int* __restrict__ csr) {
    int e = blockIdx.x * blockDim.x + threadIdx.x;
    if (e < N_EDGES) {
        int d = ei[N_EDGES + e];
        int p = atomicAdd(&fill[d], 1);
        csr[rowptr[d] + p] = ei[e];
    }
}

// ---------------------------------------------------------------------------
// Tiled VALU GEMM (encoder + fc2): C[M,N] = A[M,K] @ W[N,K]^T + bias.
// ---------------------------------------------------------------------------
template<bool RELU, bool OUT_FLAG, bool BF_COPY>
__global__ __launch_bounds__(256) void gemm_kernel(
    const void* __restrict__ A0v,
    const float* __restrict__ W0, const float* __restrict__ bias0,
    void* __restrict__ Cv, u16* __restrict__ Cbf, int M, int N, int K,
    const int* __restrict__ aflag, const int* __restrict__ oflag)
{
    __shared__ float As[16][68];
    __shared__ float Ws[16][68];
    const int tid = threadIdx.x;
    const int m0 = blockIdx.x * 64;
    const int n0 = blockIdx.y * 64;
    const int ty = tid >> 4, tx = tid & 15;
    const int lm = tid >> 2;          // 0..63
    const int k4 = (tid & 3) * 4;     // 0,4,8,12

    const bool a_bf16_rt = (aflag != nullptr) && (*aflag == 0);

    float acc[4][4] = {};

    for (int kc = 0; kc < K; kc += 16) {
        {
            int gm = m0 + lm;
            float av0 = 0.f, av1 = 0.f, av2 = 0.f, av3 = 0.f;
            if (gm < M) {
                int kg = kc + k4;
                if (a_bf16_rt) {
                    ushort4 u = *(const ushort4*)((const u16*)A0v + (size_t)gm * K + kg);
                    av0 = bf2f(u.x); av1 = bf2f(u.y); av2 = bf2f(u.z); av3 = bf2f(u.w);
                } else {
                    float4 f = *(const float4*)((const float*)A0v + (size_t)gm * K + kg);
                    av0 = f.x; av1 = f.y; av2 = f.z; av3 = f.w;
                }
            }
            As[k4 + 0][lm] = av0; As[k4 + 1][lm] = av1;
            As[k4 + 2][lm] = av2; As[k4 + 3][lm] = av3;
        }
        {
            int gn = n0 + lm;
            int kg = kc + k4;
            float4 f = *(const float4*)(W0 + (size_t)gn * K + kg);
            Ws[k4 + 0][lm] = f.x; Ws[k4 + 1][lm] = f.y;
            Ws[k4 + 2][lm] = f.z; Ws[k4 + 3][lm] = f.w;
        }
        __syncthreads();
        #pragma unroll
        for (int k = 0; k < 16; ++k) {
            float4 a = *(const float4*)&As[k][ty * 4];
            float4 b = *(const float4*)&Ws[k][tx * 4];
            float aa[4] = {a.x, a.y, a.z, a.w};
            float bb[4] = {b.x, b.y, b.z, b.w};
            #pragma unroll
            for (int i = 0; i < 4; ++i)
                #pragma unroll
                for (int j = 0; j < 4; ++j)
                    acc[i][j] += aa[i] * bb[j];
        }
        __syncthreads();
    }

    float bv[4];
    #pragma unroll
    for (int j = 0; j < 4; ++j) bv[j] = bias0[n0 + tx * 4 + j];

    const bool out_bf16 = OUT_FLAG && (*oflag == 0);

    #pragma unroll
    for (int i = 0; i < 4; ++i) {
        int gm = m0 + ty * 4 + i;
        if (gm >= M) continue;
        float o0 = acc[i][0] + bv[0], o1 = acc[i][1] + bv[1];
        float o2 = acc[i][2] + bv[2], o3 = acc[i][3] + bv[3];
        if (RELU) {
            o0 = fmaxf(o0, 0.f); o1 = fmaxf(o1, 0.f);
            o2 = fmaxf(o2, 0.f); o3 = fmaxf(o3, 0.f);
        }
        size_t co = (size_t)gm * N + n0 + tx * 4;
        if (out_bf16) {
            ushort4 u; u.x = f2bf(o0); u.y = f2bf(o1); u.z = f2bf(o2); u.w = f2bf(o3);
            *(ushort4*)((u16*)Cv + co) = u;
        } else {
            *(float4*)((float*)Cv + co) = make_float4(o0, o1, o2, o3);
        }
        if (BF_COPY) {
            ushort4 u; u.x = f2bf(o0); u.y = f2bf(o1); u.z = f2bf(o2); u.w = f2bf(o3);
            *(ushort4*)(Cbf + co) = u;
        }
    }
}

// ---------------------------------------------------------------------------
// Standalone MFMA LSTM step (t=0 forward, and backward single cell).
// Block = 32 rows, 512 threads / 8 waves; wave w owns cols q*128+w*16+[0,16).
// ---------------------------------------------------------------------------
template<bool HAS_H>
__global__ __launch_bounds__(512) void lstm_mfma_kernel(
    const u16* __restrict__ Xbf, const u16* __restrict__ hbf_in,
    u16* __restrict__ hbf_out, float* __restrict__ cf,
    const u16* __restrict__ Wswz,
    const float* __restrict__ bih, const float* __restrict__ bhh)
{
    constexpr int KK = HAS_H ? 256 : 128;
    constexpr int NCK = KK / 32;
    const int w = threadIdx.x >> 6;
    const int l = threadIdx.x & 63;
    const int l15 = l & 15, quad = l >> 4;
    const int m0 = blockIdx.x * 32;
    const int kof = quad * 8;

    f32x4 acc[2][4] = {};
    const size_t rowA0 = (size_t)(m0 + l15) * HID + kof;
    const size_t rowA1 = (size_t)(m0 + 16 + l15) * HID + kof;

    #pragma unroll
    for (int kc = 0; kc < KK; kc += 32) {
        const int ck = kc >> 5;
        const u16* Ab = (HAS_H && kc >= 128) ? hbf_in : Xbf;
        int kl = (HAS_H && kc >= 128) ? (kc - 128) : kc;
        short8 a0 = *(const short8*)(Ab + rowA0 + kl);
        short8 a1 = *(const short8*)(Ab + rowA1 + kl);
        #pragma unroll
        for (int q = 0; q < 4; ++q) {
            int nt = q * 8 + w;
            short8 b = *(const short8*)(Wswz + (((size_t)(nt * NCK + ck)) << 9) + (l << 3));
            acc[0][q] = __builtin_amdgcn_mfma_f32_16x16x32_bf16(a0, b, acc[0][q], 0, 0, 0);
            acc[1][q] = __builtin_amdgcn_mfma_f32_16x16x32_bf16(a1, b, acc[1][q], 0, 0, 0);
        }
    }

    const int j = w * 16 + l15;
    const float bI = bih[j]       + bhh[j];
    const float bF = bih[128 + j] + bhh[128 + j];
    const float bG = bih[256 + j] + bhh[256 + j];
    const float bO = bih[384 + j] + bhh[384 + j];
    #pragma unroll
    for (int mt = 0; mt < 2; ++mt) {
        #pragma unroll
        for (int i = 0; i < 4; ++i) {
            int m = m0 + mt * 16 + quad * 4 + i;
            size_t off = (size_t)m * HID + j;
            float gi = sigm(acc[mt][0][i] + bI);
            float gf = sigm(acc[mt][1][i] + bF);
            float gg = tanh_fast(acc[mt][2][i] + bG);
            float go = sigm(acc[mt][3][i] + bO);
            float cn;
            if (HAS_H) {
                cn = gf * cf[off] + gi * gg;
                cf[off] = cn;
            } else {
                cn = gi * gg;
            }
            hbf_out[off] = f2bf(go * tanh_fast(cn));
        }
    }
}

// ---------------------------------------------------------------------------
// FUSED wave + LSTM step (t>=1). Block = 32 nodes, 512 threads / 8 waves.
// Phase 1: wave w updates nodes w*4..w*4+3 sequentially (gather from XbfP
// bf16 snapshot; f32 X/Y updated IN PLACE — only own rows touched; next
// snapshot XbfN written to global; xn parked in XOR-swizzled LDS tile).
// Phase 2: MFMA LSTM, A(k<128) from LDS, A(k>=128) = hbf from global.
// LDS swizzle: (r,f) stored at col ((f>>3) ^ (r&15))*8 + (f&7): both the
// phase-1 write and the fragment read are ~2-way on banks (free, m136).
// ---------------------------------------------------------------------------
__global__ __launch_bounds__(512) void fused_wave_lstm_kernel(
    float* __restrict__ Xf, const u16* __restrict__ XbfP, u16* __restrict__ XbfN,
    float* __restrict__ Y, const float* __restrict__ degf,
    const int* __restrict__ rowptr, const int* __restrict__ csr,
    const u16* __restrict__ hbf_in, u16* __restrict__ hbf_out,
    float* __restrict__ cf, const u16* __restrict__ Wswz,
    const float* __restrict__ bih, const float* __restrict__ bhh)
{
    __shared__ u16 Axn[32][128];
    const int w = threadIdx.x >> 6;
    const int l = threadIdx.x & 63;
    const int m0 = blockIdx.x * 32;
    const int fo = l * 2;

    // ---- phase 1: wave update for this block's 32 nodes ----
    #pragma unroll
    for (int s = 0; s < 4; ++s) {
        const int r = w * 4 + s;
        const int node = m0 + r;
        const int beg = rowptr[node], end = rowptr[node + 1];
        float s0x = 0.f, s0y = 0.f, s1x = 0.f, s1y = 0.f;
        float s2x = 0.f, s2y = 0.f, s3x = 0.f, s3y = 0.f;
        int i = beg;
        for (; i + 4 <= end; i += 4) {
            int v0 = csr[i], v1 = csr[i + 1], v2 = csr[i + 2], v3 = csr[i + 3];
            ushort2 g0 = *(const ushort2*)(XbfP + (size_t)v0 * HID + fo);
            ushort2 g1 = *(const ushort2*)(XbfP + (size_t)v1 * HID + fo);
            ushort2 g2 = *(const ushort2*)(XbfP + (size_t)v2 * HID + fo);
            ushort2 g3 = *(const ushort2*)(XbfP + (size_t)v3 * HID + fo);
            s0x += bf2f(g0.x); s0y += bf2f(g0.y);
            s1x += bf2f(g1.x); s1y += bf2f(g1.y);
            s2x += bf2f(g2.x); s2y += bf2f(g2.y);
            s3x += bf2f(g3.x); s3y += bf2f(g3.y);
        }
        for (; i < end; ++i) {
            int v = csr[i];
            ushort2 g = *(const ushort2*)(XbfP + (size_t)v * HID + fo);
            s0x += bf2f(g.x); s0y += bf2f(g.y);
        }
        float ax = (s0x + s1x) + (s2x + s3x);
        float ay = (s0y + s1y) + (s2y + s3y);

        const size_t off = (size_t)node * HID + fo;
        float2 xv = *(const float2*)(Xf + off);
        float2 yv = *(const float2*)(Y + off);
        float d = degf[node];
        float y0 = yv.x - HSTEP * (d * xv.x - ax);
        float y1 = yv.y - HSTEP * (d * xv.y - ay);
        *(float2*)(Y + off) = make_float2(y0, y1);
        float xn0 = xv.x + HSTEP * y0;
        float xn1 = xv.y + HSTEP * y1;
        *(float2*)(Xf + off) = make_float2(xn0, xn1);
        ushort2 ub; ub.x = f2bf(xn0); ub.y = f2bf(xn1);
        *(ushort2*)(XbfN + off) = ub;
        *(ushort2*)(&Axn[r][(((fo >> 3) ^ r) & 15) * 8 + (fo & 7) +
                            ((fo >> 3) & ~15) * 8]) = ub;   // block-xor swizzle
    }
    __syncthreads();

    // ---- phase 2: MFMA LSTM ----
    const int l15 = l & 15, quad = l >> 4;
    const int kof = quad * 8;
    f32x4 acc[2][4] = {};
    const size_t rowH0 = (size_t)(m0 + l15) * HID + kof;
    const size_t rowH1 = (size_t)(m0 + 16 + l15) * HID + kof;

    #pragma unroll
    for (int kc = 0; kc < 256; kc += 32) {
        const int ck = kc >> 5;
        short8 a0, a1;
        if (kc < 128) {
            int b = 4 * ck + quad;            // feature block index
            a0 = *(const short8*)(&Axn[l15][((b ^ l15) & 15) * 8]);
            a1 = *(const short8*)(&Axn[16 + l15][((b ^ l15) & 15) * 8]);
        } else {
            a0 = *(const short8*)(hbf_in + rowH0 + (kc - 128));
            a1 = *(const short8*)(hbf_in + rowH1 + (kc - 128));
        }
        #pragma unroll
        for (int q = 0; q < 4; ++q) {
            int nt = q * 8 + w;
            short8 b = *(const short8*)(Wswz + (((size_t)(nt * 8 + ck)) << 9) + (l << 3));
            acc[0][q] = __builtin_amdgcn_mfma_f32_16x16x32_bf16(a0, b, acc[0][q], 0, 0, 0);
            acc[1][q] = __builtin_amdgcn_mfma_f32_16x16x32_bf16(a1, b, acc[1][q], 0, 0, 0);
        }
    }

    const int j = w * 16 + l15;
    const float bI = bih[j]       + bhh[j];
    const float bF = bih[128 + j] + bhh[128 + j];
    const float bG = bih[256 + j] + bhh[256 + j];
    const float bO = bih[384 + j] + bhh[384 + j];
    #pragma unroll
    for (int mt = 0; mt < 2; ++mt) {
        #pragma unroll
        for (int i = 0; i < 4; ++i) {
            int m = m0 + mt * 16 + quad * 4 + i;
            size_t off = (size_t)m * HID + j;
            float gi = sigm(acc[mt][0][i] + bI);
            float gf = sigm(acc[mt][1][i] + bF);
            float gg = tanh_fast(acc[mt][2][i] + bG);
            float go = sigm(acc[mt][3][i] + bO);
            float cn = gf * cf[off] + gi * gg;
            cf[off] = cn;
            hbf_out[off] = f2bf(go * tanh_fast(cn));
        }
    }
}

// ---------------------------------------------------------------------------
// fc1 MFMA: F1 = relu([hbf|hbbf] @ Wf1^T + bf1), f32 out. Inputs already bf16.
// ---------------------------------------------------------------------------
__global__ __launch_bounds__(512) void fc1_mfma_kernel(
    const u16* __restrict__ hbf, const u16* __restrict__ hbbf,
    const u16* __restrict__ WswzH, const float* __restrict__ bias,
    float* __restrict__ F1)
{
    const int w = threadIdx.x >> 6;          // nt = w (N=128 -> 8 n-tiles)
    const int l = threadIdx.x & 63;
    const int l15 = l & 15, quad = l >> 4;
    const int m0 = blockIdx.x * 32;
    const int kof = quad * 8;

    f32x4 acc[2] = {};
    #pragma unroll
    for (int kc = 0; kc < 256; kc += 32) {
        const int ck = kc >> 5;
        const u16* Ab = (kc >= 128) ? hbbf : hbf;
        int kl = (kc >= 128) ? (kc - 128) : kc;
        short8 a0 = *(const short8*)(Ab + (size_t)(m0 + l15) * HID + kl + kof);
        short8 a1 = *(const short8*)(Ab + (size_t)(m0 + 16 + l15) * HID + kl + kof);
        short8 b = *(const short8*)(WswzH + (((size_t)(w * 8 + ck)) << 9) + (l << 3));
        acc[0] = __builtin_amdgcn_mfma_f32_16x16x32_bf16(a0, b, acc[0], 0, 0, 0);
        acc[1] = __builtin_amdgcn_mfma_f32_16x16x32_bf16(a1, b, acc[1], 0, 0, 0);
    }
    const int j = w * 16 + l15;
    const float bj = bias[j];
    #pragma unroll
    for (int mt = 0; mt < 2; ++mt) {
        #pragma unroll
        for (int i = 0; i < 4; ++i) {
            int m = m0 + mt * 16 + quad * 4 + i;
            F1[(size_t)m * HID + j] = fmaxf(acc[mt][i] + bj, 0.f);
        }
    }
}

// ---------------------------------------------------------------------------
extern "C" void kernel_launch(void* const* d_in, const int* in_sizes, int n_in,
                              void* d_out, int out_size, void* d_ws, size_t ws_size,
                              hipStream_t stream)
{
    const void* x  = d_in[0];
    const int*  ei = (const int*)d_in[1];

    const size_t SZ_NH  = (size_t)N_NODES * HID * sizeof(float);   // 10,240,000
    const size_t SZ_NHB = (size_t)N_NODES * HID * sizeof(u16);     //  5,120,000
    const size_t SZ_I   = 80128;

    char* p = (char*)d_ws;
    float* Xa    = (float*)p; p += SZ_NH;
    float* Xb    = (float*)p; p += SZ_NH;      // H1 scratch, later F1
    float* Y     = (float*)p; p += SZ_NH;
    float* cf    = (float*)p; p += SZ_NH;
    u16*   hbf   = (u16*)p;   p += SZ_NHB;
    u16*   XbfA  = (u16*)p;   p += SZ_NHB;
    u16*   XbfB  = (u16*)p;   p += SZ_NHB;
    int*   deg   = (int*)p;   p += SZ_I;
    int*   fill  = (int*)p;   p += SZ_I;
    int*   rowp  = (int*)p;   p += SZ_I;
    float* degf  = (float*)p; p += SZ_I;
    int*   csr   = (int*)p;   p += (size_t)N_EDGES * sizeof(int);
    int*   flag  = (int*)p;   p += 128;
    float* wsf   = (float*)p; p += 272832 * sizeof(float);
    u16*   WswzF = (u16*)p;   p += 131072 * sizeof(u16);
    u16*   WswzB = (u16*)p;   p += 65536 * sizeof(u16);
    u16*   WswzH = (u16*)p;   p += 32768 * sizeof(u16);

    // converted f32 weight sub-pointers (offsets match cvt_off)
    float* Wenc1 = wsf + 0;
    float* benc1 = wsf + 16384;
    float* Wenc2 = wsf + 16512;
    float* benc2 = wsf + 32896;
    float* bihf  = wsf + 164096;
    float* bhhf  = wsf + 164608;
    float* bihb  = wsf + 230656;
    float* bhhb  = wsf + 231168;
    float* bf1   = wsf + 264448;
    float* Wf2   = wsf + 264576;
    float* bf2_  = wsf + 272768;

    float* H1   = Xb;        // encoder intermediate
    u16*   hbbf = (u16*)Y;   // backward h bf16; Y dead after last wave step
    float* F1   = Xb;        // head intermediate; H1 long dead

    hipMemsetAsync(Y, 0, 2 * SZ_NH + SZ_NHB, stream);   // Y, cf, hbf (contiguous)
    hipMemsetAsync(deg, 0, 2 * SZ_I, stream);           // deg, fill (contiguous)

    // dtype detect + weight conversion (f32 master, swizzled bf16 MFMA copies)
    detect_kernel<<<1, 256, 0, stream>>>((const u16*)x, flag);
    CvtArgs ca;
    ca.s[0] = d_in[2];  ca.s[1] = d_in[3];  ca.s[2] = d_in[4];  ca.s[3] = d_in[5];
    ca.s[4] = d_in[6];  ca.s[5] = d_in[7];  ca.s[6] = d_in[8];  ca.s[7] = d_in[9];
    ca.s[8] = d_in[10]; ca.s[9] = d_in[12]; ca.s[10] = d_in[13];
    ca.s[11] = d_in[14]; ca.s[12] = d_in[15]; ca.s[13] = d_in[16]; ca.s[14] = d_in[17];
    convert_kernel<<<(272832 + 255) / 256, 256, 0, stream>>>(ca, wsf, flag);
    build_wswz_kernel<<<512, 256, 0, stream>>>(wsf, WswzF, WswzB, WswzH);

    // CSR build
    count_kernel<<<(N_EDGES + 255) / 256, 256, 0, stream>>>(ei, deg);
    scan_kernel<<<1, 1024, 0, stream>>>(deg, rowp, degf);
    fill_kernel<<<(N_EDGES + 255) / 256, 256, 0, stream>>>(ei, rowp, fill, csr);

    const int MB = (N_NODES + 63) / 64;   // 313
    const int NB = N_NODES / 32;          // 625

    // encoder: H1 = relu(x @ Wenc1^T + b1); Xa = H1 @ Wenc2^T + b2 (+ bf16 copy)
    gemm_kernel<true, false, false><<<dim3(MB, 2), 256, 0, stream>>>(
        x, Wenc1, benc1, H1, nullptr, N_NODES, HID, HID, flag, nullptr);
    gemm_kernel<false, false, true><<<dim3(MB, 2), 256, 0, stream>>>(
        H1, Wenc2, benc2, Xa, XbfA, N_NODES, HID, HID, nullptr, nullptr);

    // t=0 LSTM, then 15 fused wave+LSTM steps
    lstm_mfma_kernel<true><<<NB, 512, 0, stream>>>(
        XbfA, hbf, hbf, cf, WswzF, bihf, bhhf);
    u16* XbP = XbfA;
    u16* XbN = XbfB;
    for (int t = 1; t < NSTEPS; ++t) {
        fused_wave_lstm_kernel<<<NB, 512, 0, stream>>>(
            Xa, XbP, XbN, Y, degf, rowp, csr, hbf, hbf, cf, WswzF, bihf, bhhf);
        u16* tmp = XbP; XbP = XbN; XbN = tmp;
    }

    // backward LSTM: only hs_b[0] used -> one cell on X_tilde[15], zero state
    lstm_mfma_kernel<false><<<NB, 512, 0, stream>>>(
        XbP, nullptr, hbbf, nullptr, WswzB, bihb, bhhb);

    // head: F1 = relu([hbf | hbbf] @ Wf1^T + bf1) via MFMA; out = F1 @ Wf2^T + bf2
    fc1_mfma_kernel<<<NB, 512, 0, stream>>>(hbf, hbbf, WswzH, bf1, F1);
    gemm_kernel<false, true, false><<<dim3(MB, 1), 256, 0, stream>>>(
        F1, Wf2, bf2_, d_out, nullptr, N_NODES, OUT_DIM, HID, nullptr, flag);
}

// Round 10
// 1224.907 us; speedup vs baseline: 1.1489x; 1.1489x over previous
//
#include <hip/hip_runtime.h>
#include <hip/hip_bf16.h>
#include <cstdint>
#include <cstddef>

#define N_NODES 20000
#define N_EDGES 640000
#define HID     128
#define OUT_DIM 64
#define NSTEPS  16
#define HSTEP   0.1f

typedef unsigned short u16;
typedef __attribute__((ext_vector_type(8))) short short8;   // 8 bf16 (4 VGPRs)
typedef __attribute__((ext_vector_type(4))) float f32x4;    // MFMA C/D

__device__ __forceinline__ float bf2f(u16 u) {
    union { unsigned int i; float f; } v; v.i = ((unsigned int)u) << 16; return v.f;
}
__device__ __forceinline__ u16 f2bf(float f) {
    union { float f; unsigned int i; } v; v.f = f;
    unsigned int x = v.i;
    unsigned int r = x + 0x7FFFu + ((x >> 16) & 1u);   // round-to-nearest-even
    return (u16)(r >> 16);
}

__device__ __forceinline__ float sigm(float x) { return 1.f / (1.f + __expf(-x)); }
__device__ __forceinline__ float tanh_fast(float x) {
    float e2 = __expf(-2.f * fabsf(x));
    float t = (1.f - e2) / (1.f + e2);
    return copysignf(t, x);
}

// ---------------------------------------------------------------------------
// Storage-dtype detection. flag=1 -> tensors stored as f32; flag=0 -> bf16.
// ---------------------------------------------------------------------------
__global__ void detect_kernel(const u16* __restrict__ xraw, int* __restrict__ flag) {
    __shared__ int cnt;
    if (threadIdx.x == 0) cnt = 0;
    __syncthreads();
    int c = 0;
    for (int i = threadIdx.x; i < 4096; i += 256) {
        int e = (xraw[i] >> 7) & 0xFF;
        if (e >= 0x90) c++;
    }
    atomicAdd(&cnt, c);
    __syncthreads();
    if (threadIdx.x == 0) *flag = (cnt > 100) ? 1 : 0;
}

// ---------------------------------------------------------------------------
// Packed conversion of the 15 weight/bias tensors into contiguous f32 ws.
// ---------------------------------------------------------------------------
#define N_CVT 15
struct CvtArgs { const void* s[N_CVT]; };
__constant__ const int cvt_off[N_CVT + 1] = {
    0, 16384, 16512, 32896, 33024, 98560, 164096, 164608, 165120,
    230656, 231168, 231680, 264448, 264576, 272768, 272832 };

__global__ void convert_kernel(CvtArgs a, float* __restrict__ dst,
                               const int* __restrict__ flag) {
    int i = blockIdx.x * blockDim.x + threadIdx.x;
    if (i >= 272832) return;
    int seg = 0;
    #pragma unroll
    for (int s = 1; s < N_CVT; ++s) if (i >= cvt_off[s]) seg = s;
    int j = i - cvt_off[seg];
    float v = (*flag) ? ((const float*)a.s[seg])[j]
                      : bf2f(((const u16*)a.s[seg])[j]);
    dst[i] = v;
}

// ---------------------------------------------------------------------------
// Build bf16 weights in MFMA B-fragment-swizzled order.
// elem (nt, ck, lane, j) = W[nt*16 + (lane&15)][ck*32 + (lane>>4)*8 + j]
// flat o = ((nt*NCK + ck)*64 + lane)*8 + j.
// ---------------------------------------------------------------------------
__global__ void build_wswz_kernel(const float* __restrict__ wsf,
                                  u16* __restrict__ WswzF, u16* __restrict__ WswzB,
                                  u16* __restrict__ WswzH) {
    int o = blockIdx.x * blockDim.x + threadIdx.x;
    if (o < 131072) {   // forward [Wihf|Whhf], NCK=8
        int j = o & 7, l = (o >> 3) & 63, rest = o >> 9;
        int ck = rest & 7, nt = rest >> 3;
        int n = nt * 16 + (l & 15);
        int k = ck * 32 + (l >> 4) * 8 + j;
        const float* Wihf = wsf + 33024;
        const float* Whhf = wsf + 98560;
        float v = (k < 128) ? Wihf[n * 128 + k] : Whhf[n * 128 + (k - 128)];
        WswzF[o] = f2bf(v);
    }
    if (o < 65536) {    // backward Wihb, NCK=4
        int j = o & 7, l = (o >> 3) & 63, rest = o >> 9;
        int ck = rest & 3, nt = rest >> 2;
        int n = nt * 16 + (l & 15);
        int k = ck * 32 + (l >> 4) * 8 + j;
        const float* Wihb = wsf + 165120;
        WswzB[o] = f2bf(Wihb[n * 128 + k]);
    }
    if (o < 32768) {    // fc1 Wf1 [128][256], NCK=8, nt<8
        int j = o & 7, l = (o >> 3) & 63, rest = o >> 9;
        int ck = rest & 7, nt = rest >> 3;
        int n = nt * 16 + (l & 15);
        int k = ck * 32 + (l >> 4) * 8 + j;
        const float* Wf1 = wsf + 231680;
        WswzH[o] = f2bf(Wf1[n * 256 + k]);
    }
}

// ---------------------------------------------------------------------------
// CSR build: degree count -> exclusive scan -> bucket fill
// ---------------------------------------------------------------------------
__global__ void count_kernel(const int* __restrict__ ei, int* __restrict__ deg) {
    int e = blockIdx.x * blockDim.x + threadIdx.x;
    if (e < N_EDGES) atomicAdd(&deg[ei[N_EDGES + e]], 1);
}

__global__ __launch_bounds__(1024) void scan_kernel(const int* __restrict__ deg,
                                                    int* __restrict__ rowptr,
                                                    float* __restrict__ degf) {
    __shared__ int sd[1024];
    const int t = threadIdx.x;
    const int CH = (N_NODES + 1023) / 1024;   // 20
    int base = t * CH;
    int s = 0;
    for (int i = 0; i < CH; ++i) {
        int idx = base + i;
        if (idx < N_NODES) s += deg[idx];
    }
    sd[t] = s;
    __syncthreads();
    for (int off = 1; off < 1024; off <<= 1) {
        int v = (t >= off) ? sd[t - off] : 0;
        __syncthreads();
        sd[t] += v;
        __syncthreads();
    }
    int run = (t == 0) ? 0 : sd[t - 1];
    for (int i = 0; i < CH; ++i) {
        int idx = base + i;
        if (idx < N_NODES) {
            rowptr[idx] = run;
            degf[idx] = (float)deg[idx];
            run += deg[idx];
        }
    }
    if (t == 1023) rowptr[N_NODES] = sd[1023];
}

__global__ void fill_kernel(const int* __restrict__ ei, const int* __restrict__ rowptr,
                            int* __restrict__ fill, int* __restrict__ csr) {
    int e = blockIdx.x * blockDim.x + threadIdx.x;
    if (e < N_EDGES) {
        int d = ei[N_EDGES + e];
        int p = atomicAdd(&fill[d], 1);
        csr[rowptr[d] + p] = ei[e];
    }
}

// ---------------------------------------------------------------------------
// Tiled VALU GEMM (encoder + fc2): C[M,N] = A[M,K] @ W[N,K]^T + bias.
// ---------------------------------------------------------------------------
template<bool RELU, bool OUT_FLAG, bool BF_COPY>
__global__ __launch_bounds__(256) void gemm_kernel(
    const void* __restrict__ A0v,
    const float* __restrict__ W0, const float* __restrict__ bias0,
    void* __restrict__ Cv, u16* __restrict__ Cbf, int M, int N, int K,
    const int* __restrict__ aflag, const int* __restrict__ oflag)
{
    __shared__ float As[16][68];
    __shared__ float Ws[16][68];
    const int tid = threadIdx.x;
    const int m0 = blockIdx.x * 64;
    const int n0 = blockIdx.y * 64;
    const int ty = tid >> 4, tx = tid & 15;
    const int lm = tid >> 2;
    const int k4 = (tid & 3) * 4;

    const bool a_bf16_rt = (aflag != nullptr) && (*aflag == 0);

    float acc[4][4] = {};

    for (int kc = 0; kc < K; kc += 16) {
        {
            int gm = m0 + lm;
            float av0 = 0.f, av1 = 0.f, av2 = 0.f, av3 = 0.f;
            if (gm < M) {
                int kg = kc + k4;
                if (a_bf16_rt) {
                    ushort4 u = *(const ushort4*)((const u16*)A0v + (size_t)gm * K + kg);
                    av0 = bf2f(u.x); av1 = bf2f(u.y); av2 = bf2f(u.z); av3 = bf2f(u.w);
                } else {
                    float4 f = *(const float4*)((const float*)A0v + (size_t)gm * K + kg);
                    av0 = f.x; av1 = f.y; av2 = f.z; av3 = f.w;
                }
            }
            As[k4 + 0][lm] = av0; As[k4 + 1][lm] = av1;
            As[k4 + 2][lm] = av2; As[k4 + 3][lm] = av3;
        }
        {
            int gn = n0 + lm;
            int kg = kc + k4;
            float4 f = *(const float4*)(W0 + (size_t)gn * K + kg);
            Ws[k4 + 0][lm] = f.x; Ws[k4 + 1][lm] = f.y;
            Ws[k4 + 2][lm] = f.z; Ws[k4 + 3][lm] = f.w;
        }
        __syncthreads();
        #pragma unroll
        for (int k = 0; k < 16; ++k) {
            float4 a = *(const float4*)&As[k][ty * 4];
            float4 b = *(const float4*)&Ws[k][tx * 4];
            float aa[4] = {a.x, a.y, a.z, a.w};
            float bb[4] = {b.x, b.y, b.z, b.w};
            #pragma unroll
            for (int i = 0; i < 4; ++i)
                #pragma unroll
                for (int j = 0; j < 4; ++j)
                    acc[i][j] += aa[i] * bb[j];
        }
        __syncthreads();
    }

    float bv[4];
    #pragma unroll
    for (int j = 0; j < 4; ++j) bv[j] = bias0[n0 + tx * 4 + j];

    const bool out_bf16 = OUT_FLAG && (*oflag == 0);

    #pragma unroll
    for (int i = 0; i < 4; ++i) {
        int gm = m0 + ty * 4 + i;
        if (gm >= M) continue;
        float o0 = acc[i][0] + bv[0], o1 = acc[i][1] + bv[1];
        float o2 = acc[i][2] + bv[2], o3 = acc[i][3] + bv[3];
        if (RELU) {
            o0 = fmaxf(o0, 0.f); o1 = fmaxf(o1, 0.f);
            o2 = fmaxf(o2, 0.f); o3 = fmaxf(o3, 0.f);
        }
        size_t co = (size_t)gm * N + n0 + tx * 4;
        if (out_bf16) {
            ushort4 u; u.x = f2bf(o0); u.y = f2bf(o1); u.z = f2bf(o2); u.w = f2bf(o3);
            *(ushort4*)((u16*)Cv + co) = u;
        } else {
            *(float4*)((float*)Cv + co) = make_float4(o0, o1, o2, o3);
        }
        if (BF_COPY) {
            ushort4 u; u.x = f2bf(o0); u.y = f2bf(o1); u.z = f2bf(o2); u.w = f2bf(o3);
            *(ushort4*)(Cbf + co) = u;
        }
    }
}

// ---------------------------------------------------------------------------
// LSTM body (HAS_H=true), 512 threads / 8 waves, 32 rows per call.
// Wave w owns cols q*128 + w*16 + [0,16) (nt = q*8 + w); B from WswzF
// (wave-uniform base + lane*16B). h/c updated in place (own rows only).
// ---------------------------------------------------------------------------
__device__ __forceinline__ void lstm_body_fwd(
    int bx, const u16* Xbf, u16* hbf, float* cf,
    const u16* Wswz, const float* bih, const float* bhh)
{
    const int w = threadIdx.x >> 6;
    const int l = threadIdx.x & 63;
    const int l15 = l & 15, quad = l >> 4;
    const int m0 = bx * 32;
    const int kof = quad * 8;

    f32x4 acc[2][4] = {};
    const size_t rowA0 = (size_t)(m0 + l15) * HID + kof;
    const size_t rowA1 = (size_t)(m0 + 16 + l15) * HID + kof;

    #pragma unroll
    for (int kc = 0; kc < 256; kc += 32) {
        const int ck = kc >> 5;
        const u16* Ab = (kc >= 128) ? hbf : Xbf;
        int kl = (kc >= 128) ? (kc - 128) : kc;
        short8 a0 = *(const short8*)(Ab + rowA0 + kl);
        short8 a1 = *(const short8*)(Ab + rowA1 + kl);
        #pragma unroll
        for (int q = 0; q < 4; ++q) {
            int nt = q * 8 + w;
            short8 b = *(const short8*)(Wswz + (((size_t)(nt * 8 + ck)) << 9) + (l << 3));
            acc[0][q] = __builtin_amdgcn_mfma_f32_16x16x32_bf16(a0, b, acc[0][q], 0, 0, 0);
            acc[1][q] = __builtin_amdgcn_mfma_f32_16x16x32_bf16(a1, b, acc[1][q], 0, 0, 0);
        }
    }

    const int j = w * 16 + l15;
    const float bI = bih[j]       + bhh[j];
    const float bF = bih[128 + j] + bhh[128 + j];
    const float bG = bih[256 + j] + bhh[256 + j];
    const float bO = bih[384 + j] + bhh[384 + j];
    #pragma unroll
    for (int mt = 0; mt < 2; ++mt) {
        #pragma unroll
        for (int i = 0; i < 4; ++i) {
            int m = m0 + mt * 16 + quad * 4 + i;
            size_t off = (size_t)m * HID + j;
            float gi = sigm(acc[mt][0][i] + bI);
            float gf = sigm(acc[mt][1][i] + bF);
            float gg = tanh_fast(acc[mt][2][i] + bG);
            float go = sigm(acc[mt][3][i] + bO);
            float cn = gf * cf[off] + gi * gg;
            cf[off] = cn;
            hbf[off] = f2bf(go * tanh_fast(cn));
        }
    }
}

// ---------------------------------------------------------------------------
// Wave body: ONE node per wave (full gather TLP), lane holds float2.
// Gathers from bf16 XbfP; f32 X/Y updated in place (own row only);
// next bf16 snapshot written to XbfN. 4-edge unroll for MLP.
// ---------------------------------------------------------------------------
__device__ __forceinline__ void wave_body(
    int wb, float* Xf, const u16* XbfP, u16* XbfN, float* Y,
    const float* degf, const int* rowptr, const int* csr)
{
    const int w = threadIdx.x >> 6;
    const int node = wb * 8 + w;
    const int lane = threadIdx.x & 63;
    const int fo = lane * 2;

    const int beg = rowptr[node], end = rowptr[node + 1];
    float s0x = 0.f, s0y = 0.f, s1x = 0.f, s1y = 0.f;
    float s2x = 0.f, s2y = 0.f, s3x = 0.f, s3y = 0.f;

    int i = beg;
    for (; i + 4 <= end; i += 4) {
        int v0 = csr[i], v1 = csr[i + 1], v2 = csr[i + 2], v3 = csr[i + 3];
        ushort2 g0 = *(const ushort2*)(XbfP + (size_t)v0 * HID + fo);
        ushort2 g1 = *(const ushort2*)(XbfP + (size_t)v1 * HID + fo);
        ushort2 g2 = *(const ushort2*)(XbfP + (size_t)v2 * HID + fo);
        ushort2 g3 = *(const ushort2*)(XbfP + (size_t)v3 * HID + fo);
        s0x += bf2f(g0.x); s0y += bf2f(g0.y);
        s1x += bf2f(g1.x); s1y += bf2f(g1.y);
        s2x += bf2f(g2.x); s2y += bf2f(g2.y);
        s3x += bf2f(g3.x); s3y += bf2f(g3.y);
    }
    for (; i < end; ++i) {
        int v = csr[i];
        ushort2 g = *(const ushort2*)(XbfP + (size_t)v * HID + fo);
        s0x += bf2f(g.x); s0y += bf2f(g.y);
    }
    float ax = (s0x + s1x) + (s2x + s3x);
    float ay = (s0y + s1y) + (s2y + s3y);

    const size_t off = (size_t)node * HID + fo;
    float2 xv = *(const float2*)(Xf + off);
    float2 yv = *(const float2*)(Y + off);
    float d = degf[node];
    float y0 = yv.x - HSTEP * (d * xv.x - ax);
    float y1 = yv.y - HSTEP * (d * xv.y - ay);
    *(float2*)(Y + off) = make_float2(y0, y1);
    float xn0 = xv.x + HSTEP * y0;
    float xn1 = xv.y + HSTEP * y1;
    *(float2*)(Xf + off) = make_float2(xn0, xn1);
    ushort2 ub; ub.x = f2bf(xn0); ub.y = f2bf(xn1);
    *(ushort2*)(XbfN + off) = ub;
}

// ---------------------------------------------------------------------------
// Combined step launch: blocks [0,625) = LSTM step t (reads XbP, h/c in
// place); blocks [625,3125) = wave computing X_{t+1} (gathers XbP, writes
// XbN + in-place f32 X/Y). The two populations are data-independent within
// a launch; HW co-schedules gather-bound and MFMA-bound waves (m114).
// Last step launches with grid=625 (LSTM only).
// ---------------------------------------------------------------------------
__global__ __launch_bounds__(512) void step_kernel(
    float* Xf, const u16* XbP, u16* XbN, float* Y,
    const float* __restrict__ degf, const int* __restrict__ rowp,
    const int* __restrict__ csr,
    u16* hbf, float* cf, const u16* __restrict__ WswzF,
    const float* __restrict__ bih, const float* __restrict__ bhh)
{
    if (blockIdx.x < 625) {
        lstm_body_fwd(blockIdx.x, XbP, hbf, cf, WswzF, bih, bhh);
    } else {
        wave_body(blockIdx.x - 625, Xf, XbP, XbN, Y, degf, rowp, csr);
    }
}

// ---------------------------------------------------------------------------
// Standalone MFMA LSTM (backward single cell, zero state). KK=128.
// ---------------------------------------------------------------------------
__global__ __launch_bounds__(512) void lstm_bwd_kernel(
    const u16* __restrict__ Xbf, u16* __restrict__ hbf_out,
    const u16* __restrict__ Wswz,
    const float* __restrict__ bih, const float* __restrict__ bhh)
{
    const int w = threadIdx.x >> 6;
    const int l = threadIdx.x & 63;
    const int l15 = l & 15, quad = l >> 4;
    const int m0 = blockIdx.x * 32;
    const int kof = quad * 8;

    f32x4 acc[2][4] = {};
    const size_t rowA0 = (size_t)(m0 + l15) * HID + kof;
    const size_t rowA1 = (size_t)(m0 + 16 + l15) * HID + kof;

    #pragma unroll
    for (int kc = 0; kc < 128; kc += 32) {
        const int ck = kc >> 5;
        short8 a0 = *(const short8*)(Xbf + rowA0 + kc);
        short8 a1 = *(const short8*)(Xbf + rowA1 + kc);
        #pragma unroll
        for (int q = 0; q < 4; ++q) {
            int nt = q * 8 + w;
            short8 b = *(const short8*)(Wswz + (((size_t)(nt * 4 + ck)) << 9) + (l << 3));
            acc[0][q] = __builtin_amdgcn_mfma_f32_16x16x32_bf16(a0, b, acc[0][q], 0, 0, 0);
            acc[1][q] = __builtin_amdgcn_mfma_f32_16x16x32_bf16(a1, b, acc[1][q], 0, 0, 0);
        }
    }

    const int j = w * 16 + l15;
    const float bI = bih[j]       + bhh[j];
    const float bF = bih[128 + j] + bhh[128 + j];
    const float bG = bih[256 + j] + bhh[256 + j];
    const float bO = bih[384 + j] + bhh[384 + j];
    #pragma unroll
    for (int mt = 0; mt < 2; ++mt) {
        #pragma unroll
        for (int i = 0; i < 4; ++i) {
            int m = m0 + mt * 16 + quad * 4 + i;
            size_t off = (size_t)m * HID + j;
            float gi = sigm(acc[mt][0][i] + bI);
            float gf = sigm(acc[mt][1][i] + bF); (void)gf;
            float gg = tanh_fast(acc[mt][2][i] + bG);
            float go = sigm(acc[mt][3][i] + bO);
            float cn = gi * gg;
            hbf_out[off] = f2bf(go * tanh_fast(cn));
        }
    }
}

// ---------------------------------------------------------------------------
// fc1 MFMA: F1 = relu([hbf|hbbf] @ Wf1^T + bf1), f32 out.
// ---------------------------------------------------------------------------
__global__ __launch_bounds__(512) void fc1_mfma_kernel(
    const u16* __restrict__ hbf, const u16* __restrict__ hbbf,
    const u16* __restrict__ WswzH, const float* __restrict__ bias,
    float* __restrict__ F1)
{
    const int w = threadIdx.x >> 6;
    const int l = threadIdx.x & 63;
    const int l15 = l & 15, quad = l >> 4;
    const int m0 = blockIdx.x * 32;
    const int kof = quad * 8;

    f32x4 acc[2] = {};
    #pragma unroll
    for (int kc = 0; kc < 256; kc += 32) {
        const int ck = kc >> 5;
        const u16* Ab = (kc >= 128) ? hbbf : hbf;
        int kl = (kc >= 128) ? (kc - 128) : kc;
        short8 a0 = *(const short8*)(Ab + (size_t)(m0 + l15) * HID + kl + kof);
        short8 a1 = *(const short8*)(Ab + (size_t)(m0 + 16 + l15) * HID + kl + kof);
        short8 b = *(const short8*)(WswzH + (((size_t)(w * 8 + ck)) << 9) + (l << 3));
        acc[0] = __builtin_amdgcn_mfma_f32_16x16x32_bf16(a0, b, acc[0], 0, 0, 0);
        acc[1] = __builtin_amdgcn_mfma_f32_16x16x32_bf16(a1, b, acc[1], 0, 0, 0);
    }
    const int j = w * 16 + l15;
    const float bj = bias[j];
    #pragma unroll
    for (int mt = 0; mt < 2; ++mt) {
        #pragma unroll
        for (int i = 0; i < 4; ++i) {
            int m = m0 + mt * 16 + quad * 4 + i;
            F1[(size_t)m * HID + j] = fmaxf(acc[mt][i] + bj, 0.f);
        }
    }
}

// ---------------------------------------------------------------------------
extern "C" void kernel_launch(void* const* d_in, const int* in_sizes, int n_in,
                              void* d_out, int out_size, void* d_ws, size_t ws_size,
                              hipStream_t stream)
{
    const void* x  = d_in[0];
    const int*  ei = (const int*)d_in[1];

    const size_t SZ_NH  = (size_t)N_NODES * HID * sizeof(float);   // 10,240,000
    const size_t SZ_NHB = (size_t)N_NODES * HID * sizeof(u16);     //  5,120,000
    const size_t SZ_I   = 80128;

    char* p = (char*)d_ws;
    float* Xa    = (float*)p; p += SZ_NH;
    float* Xb    = (float*)p; p += SZ_NH;      // H1 scratch, later F1
    float* Y     = (float*)p; p += SZ_NH;
    float* cf    = (float*)p; p += SZ_NH;
    u16*   hbf   = (u16*)p;   p += SZ_NHB;
    u16*   XbfA  = (u16*)p;   p += SZ_NHB;
    u16*   XbfB  = (u16*)p;   p += SZ_NHB;
    int*   deg   = (int*)p;   p += SZ_I;
    int*   fill  = (int*)p;   p += SZ_I;
    int*   rowp  = (int*)p;   p += SZ_I;
    float* degf  = (float*)p; p += SZ_I;
    int*   csr   = (int*)p;   p += (size_t)N_EDGES * sizeof(int);
    int*   flag  = (int*)p;   p += 128;
    float* wsf   = (float*)p; p += 272832 * sizeof(float);
    u16*   WswzF = (u16*)p;   p += 131072 * sizeof(u16);
    u16*   WswzB = (u16*)p;   p += 65536 * sizeof(u16);
    u16*   WswzH = (u16*)p;   p += 32768 * sizeof(u16);

    // converted f32 weight sub-pointers (offsets match cvt_off)
    float* Wenc1 = wsf + 0;
    float* benc1 = wsf + 16384;
    float* Wenc2 = wsf + 16512;
    float* benc2 = wsf + 32896;
    float* bihf  = wsf + 164096;
    float* bhhf  = wsf + 164608;
    float* bihb  = wsf + 230656;
    float* bhhb  = wsf + 231168;
    float* bf1   = wsf + 264448;
    float* Wf2   = wsf + 264576;
    float* bf2_  = wsf + 272768;

    float* H1   = Xb;        // encoder intermediate
    u16*   hbbf = (u16*)Y;   // backward h bf16; Y dead after last wave step
    float* F1   = Xb;        // head intermediate; H1 long dead

    hipMemsetAsync(Y, 0, 2 * SZ_NH + SZ_NHB, stream);   // Y, cf, hbf (contiguous)
    hipMemsetAsync(deg, 0, 2 * SZ_I, stream);           // deg, fill (contiguous)

    // dtype detect + weight conversion (f32 master, swizzled bf16 MFMA copies)
    detect_kernel<<<1, 256, 0, stream>>>((const u16*)x, flag);
    CvtArgs ca;
    ca.s[0] = d_in[2];  ca.s[1] = d_in[3];  ca.s[2] = d_in[4];  ca.s[3] = d_in[5];
    ca.s[4] = d_in[6];  ca.s[5] = d_in[7];  ca.s[6] = d_in[8];  ca.s[7] = d_in[9];
    ca.s[8] = d_in[10]; ca.s[9] = d_in[12]; ca.s[10] = d_in[13];
    ca.s[11] = d_in[14]; ca.s[12] = d_in[15]; ca.s[13] = d_in[16]; ca.s[14] = d_in[17];
    convert_kernel<<<(272832 + 255) / 256, 256, 0, stream>>>(ca, wsf, flag);
    build_wswz_kernel<<<512, 256, 0, stream>>>(wsf, WswzF, WswzB, WswzH);

    // CSR build
    count_kernel<<<(N_EDGES + 255) / 256, 256, 0, stream>>>(ei, deg);
    scan_kernel<<<1, 1024, 0, stream>>>(deg, rowp, degf);
    fill_kernel<<<(N_EDGES + 255) / 256, 256, 0, stream>>>(ei, rowp, fill, csr);

    const int MB = (N_NODES + 63) / 64;   // 313
    const int NB = N_NODES / 32;          // 625

    // encoder: H1 = relu(x @ Wenc1^T + b1); Xa = H1 @ Wenc2^T + b2 (+ bf16 copy)
    gemm_kernel<true, false, false><<<dim3(MB, 2), 256, 0, stream>>>(
        x, Wenc1, benc1, H1, nullptr, N_NODES, HID, HID, flag, nullptr);
    gemm_kernel<false, false, true><<<dim3(MB, 2), 256, 0, stream>>>(
        H1, Wenc2, benc2, Xa, XbfA, N_NODES, HID, HID, nullptr, nullptr);

    // combined steps: launch t = LSTM(t) blocks + wave(t+1) blocks
    u16* XbP = XbfA;
    u16* XbN = XbfB;
    for (int t = 0; t < NSTEPS; ++t) {
        int grid = (t < NSTEPS - 1) ? (NB + 2500) : NB;
        step_kernel<<<grid, 512, 0, stream>>>(
            Xa, XbP, XbN, Y, degf, rowp, csr, hbf, cf, WswzF, bihf, bhhf);
        if (t < NSTEPS - 1) { u16* tmp = XbP; XbP = XbN; XbN = tmp; }
    }

    // backward LSTM: only hs_b[0] used -> one cell on X_tilde[15], zero state
    lstm_bwd_kernel<<<NB, 512, 0, stream>>>(XbP, hbbf, WswzB, bihb, bhhb);

    // head: F1 = relu([hbf | hbbf] @ Wf1^T + bf1) via MFMA; out = F1 @ Wf2^T + bf2
    fc1_mfma_kernel<<<NB, 512, 0, stream>>>(hbf, hbbf, WswzH, bf1, F1);
    gemm_kernel<false, true, false><<<dim3(MB, 1), 256, 0, stream>>>(
        F1, Wf2, bf2_, d_out, nullptr, N_NODES, OUT_DIM, HID, nullptr, flag);
}

// Round 11
// 1020.702 us; speedup vs baseline: 1.3787x; 1.2001x over previous
//
#include <hip/hip_runtime.h>
#include <hip/hip_bf16.h>
#include <cstdint>
#include <cstddef>

#define N_NODES 20000
#define N_EDGES 640000
#define HID     128
#define OUT_DIM 64
#define NSTEPS  16
#define HSTEP   0.1f

typedef unsigned short u16;
typedef __attribute__((ext_vector_type(8))) short short8;   // 8 bf16 (4 VGPRs)
typedef __attribute__((ext_vector_type(4))) float f32x4;    // MFMA C/D

__device__ __forceinline__ float bf2f(u16 u) {
    union { unsigned int i; float f; } v; v.i = ((unsigned int)u) << 16; return v.f;
}
__device__ __forceinline__ u16 f2bf(float f) {
    union { float f; unsigned int i; } v; v.f = f;
    unsigned int x = v.i;
    unsigned int r = x + 0x7FFFu + ((x >> 16) & 1u);   // round-to-nearest-even
    return (u16)(r >> 16);
}

__device__ __forceinline__ float sigm(float x) { return 1.f / (1.f + __expf(-x)); }
__device__ __forceinline__ float tanh_fast(float x) {
    float e2 = __expf(-2.f * fabsf(x));
    float t = (1.f - e2) / (1.f + e2);
    return copysignf(t, x);
}

// ---------------------------------------------------------------------------
// Storage-dtype detection. flag=1 -> tensors stored as f32; flag=0 -> bf16.
// ---------------------------------------------------------------------------
__global__ void detect_kernel(const u16* __restrict__ xraw, int* __restrict__ flag) {
    __shared__ int cnt;
    if (threadIdx.x == 0) cnt = 0;
    __syncthreads();
    int c = 0;
    for (int i = threadIdx.x; i < 4096; i += 256) {
        int e = (xraw[i] >> 7) & 0xFF;
        if (e >= 0x90) c++;
    }
    atomicAdd(&cnt, c);
    __syncthreads();
    if (threadIdx.x == 0) *flag = (cnt > 100) ? 1 : 0;
}

// ---------------------------------------------------------------------------
// Packed conversion of the 15 weight/bias tensors into contiguous f32 ws.
// ---------------------------------------------------------------------------
#define N_CVT 15
struct CvtArgs { const void* s[N_CVT]; };
__constant__ const int cvt_off[N_CVT + 1] = {
    0, 16384, 16512, 32896, 33024, 98560, 164096, 164608, 165120,
    230656, 231168, 231680, 264448, 264576, 272768, 272832 };

__global__ void convert_kernel(CvtArgs a, float* __restrict__ dst,
                               const int* __restrict__ flag) {
    int i = blockIdx.x * blockDim.x + threadIdx.x;
    if (i >= 272832) return;
    int seg = 0;
    #pragma unroll
    for (int s = 1; s < N_CVT; ++s) if (i >= cvt_off[s]) seg = s;
    int j = i - cvt_off[seg];
    float v = (*flag) ? ((const float*)a.s[seg])[j]
                      : bf2f(((const u16*)a.s[seg])[j]);
    dst[i] = v;
}

// ---------------------------------------------------------------------------
// Build bf16 weights in MFMA B-fragment-swizzled order.
// elem (nt, ck, lane, j) = W[nt*16 + (lane&15)][ck*32 + (lane>>4)*8 + j]
// flat o = ((nt*NCK + ck)*64 + lane)*8 + j.
// WswzF: [Wihf|Whhf] K=256; WswzB: Wihb K=128; WswzH: Wf1 K=256; WswzO: Wf2 K=128.
// ---------------------------------------------------------------------------
__global__ void build_wswz_kernel(const float* __restrict__ wsf,
                                  u16* __restrict__ WswzF, u16* __restrict__ WswzB,
                                  u16* __restrict__ WswzH, u16* __restrict__ WswzO) {
    int o = blockIdx.x * blockDim.x + threadIdx.x;
    if (o < 131072) {   // forward [Wihf|Whhf], NCK=8
        int j = o & 7, l = (o >> 3) & 63, rest = o >> 9;
        int ck = rest & 7, nt = rest >> 3;
        int n = nt * 16 + (l & 15);
        int k = ck * 32 + (l >> 4) * 8 + j;
        const float* Wihf = wsf + 33024;
        const float* Whhf = wsf + 98560;
        float v = (k < 128) ? Wihf[n * 128 + k] : Whhf[n * 128 + (k - 128)];
        WswzF[o] = f2bf(v);
    }
    if (o < 65536) {    // backward Wihb, NCK=4
        int j = o & 7, l = (o >> 3) & 63, rest = o >> 9;
        int ck = rest & 3, nt = rest >> 2;
        int n = nt * 16 + (l & 15);
        int k = ck * 32 + (l >> 4) * 8 + j;
        const float* Wihb = wsf + 165120;
        WswzB[o] = f2bf(Wihb[n * 128 + k]);
    }
    if (o < 32768) {    // fc1 Wf1 [128][256], NCK=8, nt<8
        int j = o & 7, l = (o >> 3) & 63, rest = o >> 9;
        int ck = rest & 7, nt = rest >> 3;
        int n = nt * 16 + (l & 15);
        int k = ck * 32 + (l >> 4) * 8 + j;
        const float* Wf1 = wsf + 231680;
        WswzH[o] = f2bf(Wf1[n * 256 + k]);
    }
    if (o < 8192) {     // fc2 Wf2 [64][128], NCK=4, nt<4
        int j = o & 7, l = (o >> 3) & 63, rest = o >> 9;
        int ck = rest & 3, nt = rest >> 2;
        int n = nt * 16 + (l & 15);
        int k = ck * 32 + (l >> 4) * 8 + j;
        const float* Wf2 = wsf + 264576;
        WswzO[o] = f2bf(Wf2[n * 128 + k]);
    }
}

// ---------------------------------------------------------------------------
// CSR build: degree count -> exclusive scan -> bucket fill
// ---------------------------------------------------------------------------
__global__ void count_kernel(const int* __restrict__ ei, int* __restrict__ deg) {
    int e = blockIdx.x * blockDim.x + threadIdx.x;
    if (e < N_EDGES) atomicAdd(&deg[ei[N_EDGES + e]], 1);
}

__global__ __launch_bounds__(1024) void scan_kernel(const int* __restrict__ deg,
                                                    int* __restrict__ rowptr,
                                                    float* __restrict__ degf) {
    __shared__ int sd[1024];
    const int t = threadIdx.x;
    const int CH = (N_NODES + 1023) / 1024;   // 20
    int base = t * CH;
    int s = 0;
    for (int i = 0; i < CH; ++i) {
        int idx = base + i;
        if (idx < N_NODES) s += deg[idx];
    }
    sd[t] = s;
    __syncthreads();
    for (int off = 1; off < 1024; off <<= 1) {
        int v = (t >= off) ? sd[t - off] : 0;
        __syncthreads();
        sd[t] += v;
        __syncthreads();
    }
    int run = (t == 0) ? 0 : sd[t - 1];
    for (int i = 0; i < CH; ++i) {
        int idx = base + i;
        if (idx < N_NODES) {
            rowptr[idx] = run;
            degf[idx] = (float)deg[idx];
            run += deg[idx];
        }
    }
    if (t == 1023) rowptr[N_NODES] = sd[1023];
}

__global__ void fill_kernel(const int* __restrict__ ei, const int* __restrict__ rowptr,
                            int* __restrict__ fill, int* __restrict__ csr) {
    int e = blockIdx.x * blockDim.x + threadIdx.x;
    if (e < N_EDGES) {
        int d = ei[N_EDGES + e];
        int p = atomicAdd(&fill[d], 1);
        csr[rowptr[d] + p] = ei[e];
    }
}

// ---------------------------------------------------------------------------
// Tiled VALU GEMM (encoder only): C[M,N] = A[M,K] @ W[N,K]^T + bias.
// ---------------------------------------------------------------------------
template<bool RELU, bool BF_COPY>
__global__ __launch_bounds__(256) void gemm_kernel(
    const void* __restrict__ A0v,
    const float* __restrict__ W0, const float* __restrict__ bias0,
    float* __restrict__ Cv, u16* __restrict__ Cbf, int M, int N, int K,
    const int* __restrict__ aflag)
{
    __shared__ float As[16][68];
    __shared__ float Ws[16][68];
    const int tid = threadIdx.x;
    const int m0 = blockIdx.x * 64;
    const int n0 = blockIdx.y * 64;
    const int ty = tid >> 4, tx = tid & 15;
    const int lm = tid >> 2;
    const int k4 = (tid & 3) * 4;

    const bool a_bf16_rt = (aflag != nullptr) && (*aflag == 0);

    float acc[4][4] = {};

    for (int kc = 0; kc < K; kc += 16) {
        {
            int gm = m0 + lm;
            float av0 = 0.f, av1 = 0.f, av2 = 0.f, av3 = 0.f;
            if (gm < M) {
                int kg = kc + k4;
                if (a_bf16_rt) {
                    ushort4 u = *(const ushort4*)((const u16*)A0v + (size_t)gm * K + kg);
                    av0 = bf2f(u.x); av1 = bf2f(u.y); av2 = bf2f(u.z); av3 = bf2f(u.w);
                } else {
                    float4 f = *(const float4*)((const float*)A0v + (size_t)gm * K + kg);
                    av0 = f.x; av1 = f.y; av2 = f.z; av3 = f.w;
                }
            }
            As[k4 + 0][lm] = av0; As[k4 + 1][lm] = av1;
            As[k4 + 2][lm] = av2; As[k4 + 3][lm] = av3;
        }
        {
            int gn = n0 + lm;
            int kg = kc + k4;
            float4 f = *(const float4*)(W0 + (size_t)gn * K + kg);
            Ws[k4 + 0][lm] = f.x; Ws[k4 + 1][lm] = f.y;
            Ws[k4 + 2][lm] = f.z; Ws[k4 + 3][lm] = f.w;
        }
        __syncthreads();
        #pragma unroll
        for (int k = 0; k < 16; ++k) {
            float4 a = *(const float4*)&As[k][ty * 4];
            float4 b = *(const float4*)&Ws[k][tx * 4];
            float aa[4] = {a.x, a.y, a.z, a.w};
            float bb[4] = {b.x, b.y, b.z, b.w};
            #pragma unroll
            for (int i = 0; i < 4; ++i)
                #pragma unroll
                for (int j = 0; j < 4; ++j)
                    acc[i][j] += aa[i] * bb[j];
        }
        __syncthreads();
    }

    float bv[4];
    #pragma unroll
    for (int j = 0; j < 4; ++j) bv[j] = bias0[n0 + tx * 4 + j];

    #pragma unroll
    for (int i = 0; i < 4; ++i) {
        int gm = m0 + ty * 4 + i;
        if (gm >= M) continue;
        float o0 = acc[i][0] + bv[0], o1 = acc[i][1] + bv[1];
        float o2 = acc[i][2] + bv[2], o3 = acc[i][3] + bv[3];
        if (RELU) {
            o0 = fmaxf(o0, 0.f); o1 = fmaxf(o1, 0.f);
            o2 = fmaxf(o2, 0.f); o3 = fmaxf(o3, 0.f);
        }
        size_t co = (size_t)gm * N + n0 + tx * 4;
        *(float4*)(Cv + co) = make_float4(o0, o1, o2, o3);
        if (BF_COPY) {
            ushort4 u; u.x = f2bf(o0); u.y = f2bf(o1); u.z = f2bf(o2); u.w = f2bf(o3);
            *(ushort4*)(Cbf + co) = u;
        }
    }
}

// ---------------------------------------------------------------------------
// Forward MFMA LSTM step. 512 threads / 8 waves, 32 rows per block.
// Wave w owns cols q*128 + w*16 + [0,16) (nt = q*8 + w); B from WswzF
// (wave-uniform base + lane*16B). h/c updated in place (own rows only).
// ---------------------------------------------------------------------------
__global__ __launch_bounds__(512) void lstm_fwd_kernel(
    const u16* __restrict__ Xbf, u16* hbf, float* cf,
    const u16* __restrict__ Wswz,
    const float* __restrict__ bih, const float* __restrict__ bhh)
{
    const int w = threadIdx.x >> 6;
    const int l = threadIdx.x & 63;
    const int l15 = l & 15, quad = l >> 4;
    const int m0 = blockIdx.x * 32;
    const int kof = quad * 8;

    f32x4 acc[2][4] = {};
    const size_t rowA0 = (size_t)(m0 + l15) * HID + kof;
    const size_t rowA1 = (size_t)(m0 + 16 + l15) * HID + kof;

    #pragma unroll
    for (int kc = 0; kc < 256; kc += 32) {
        const int ck = kc >> 5;
        const u16* Ab = (kc >= 128) ? hbf : Xbf;
        int kl = (kc >= 128) ? (kc - 128) : kc;
        short8 a0 = *(const short8*)(Ab + rowA0 + kl);
        short8 a1 = *(const short8*)(Ab + rowA1 + kl);
        #pragma unroll
        for (int q = 0; q < 4; ++q) {
            int nt = q * 8 + w;
            short8 b = *(const short8*)(Wswz + (((size_t)(nt * 8 + ck)) << 9) + (l << 3));
            acc[0][q] = __builtin_amdgcn_mfma_f32_16x16x32_bf16(a0, b, acc[0][q], 0, 0, 0);
            acc[1][q] = __builtin_amdgcn_mfma_f32_16x16x32_bf16(a1, b, acc[1][q], 0, 0, 0);
        }
    }

    const int j = w * 16 + l15;
    const float bI = bih[j]       + bhh[j];
    const float bF = bih[128 + j] + bhh[128 + j];
    const float bG = bih[256 + j] + bhh[256 + j];
    const float bO = bih[384 + j] + bhh[384 + j];
    #pragma unroll
    for (int mt = 0; mt < 2; ++mt) {
        #pragma unroll
        for (int i = 0; i < 4; ++i) {
            int m = m0 + mt * 16 + quad * 4 + i;
            size_t off = (size_t)m * HID + j;
            float gi = sigm(acc[mt][0][i] + bI);
            float gf = sigm(acc[mt][1][i] + bF);
            float gg = tanh_fast(acc[mt][2][i] + bG);
            float go = sigm(acc[mt][3][i] + bO);
            float cn = gf * cf[off] + gi * gg;
            cf[off] = cn;
            hbf[off] = f2bf(go * tanh_fast(cn));
        }
    }
}

// ---------------------------------------------------------------------------
// Wave step v5: one node per wave; PAIRED-EDGE gather — lanes 0-31 take edge
// A, lanes 32-63 edge B, each lane ushort4 (4 feats, 8B). 4-pair unroll ->
// 8 edges in flight per wave (2x MLP vs v4). Cross-half __shfl_xor merge.
// f32 X/Y updated in place (own row only); bf16 snapshot to XbfN.
// ---------------------------------------------------------------------------
__global__ __launch_bounds__(256) void wave_kernel(
    float* __restrict__ Xf, const u16* __restrict__ XbfP, u16* __restrict__ XbfN,
    float* __restrict__ Y, const float* __restrict__ degf,
    const int* __restrict__ rowptr, const int* __restrict__ csr)
{
    const int node = blockIdx.x * 4 + (threadIdx.x >> 6);
    const int lane = threadIdx.x & 63;
    const int half = lane >> 5;          // 0: edge A, 1: edge B
    const int fl = (lane & 31) * 4;      // 4 features per lane

    const int beg = rowptr[node], end = rowptr[node + 1];
    float a0x = 0.f, a0y = 0.f, a0z = 0.f, a0w = 0.f;
    float a1x = 0.f, a1y = 0.f, a1z = 0.f, a1w = 0.f;
    float a2x = 0.f, a2y = 0.f, a2z = 0.f, a2w = 0.f;
    float a3x = 0.f, a3y = 0.f, a3z = 0.f, a3w = 0.f;

    int i = beg;
    for (; i + 8 <= end; i += 8) {
        int v0 = csr[i + 0 + half];
        int v1 = csr[i + 2 + half];
        int v2 = csr[i + 4 + half];
        int v3 = csr[i + 6 + half];
        ushort4 g0 = *(const ushort4*)(XbfP + (size_t)v0 * HID + fl);
        ushort4 g1 = *(const ushort4*)(XbfP + (size_t)v1 * HID + fl);
        ushort4 g2 = *(const ushort4*)(XbfP + (size_t)v2 * HID + fl);
        ushort4 g3 = *(const ushort4*)(XbfP + (size_t)v3 * HID + fl);
        a0x += bf2f(g0.x); a0y += bf2f(g0.y); a0z += bf2f(g0.z); a0w += bf2f(g0.w);
        a1x += bf2f(g1.x); a1y += bf2f(g1.y); a1z += bf2f(g1.z); a1w += bf2f(g1.w);
        a2x += bf2f(g2.x); a2y += bf2f(g2.y); a2z += bf2f(g2.z); a2w += bf2f(g2.w);
        a3x += bf2f(g3.x); a3y += bf2f(g3.y); a3z += bf2f(g3.z); a3w += bf2f(g3.w);
    }
    for (; i + 2 <= end; i += 2) {       // pair tail
        int v = csr[i + half];
        ushort4 g = *(const ushort4*)(XbfP + (size_t)v * HID + fl);
        a0x += bf2f(g.x); a0y += bf2f(g.y); a0z += bf2f(g.z); a0w += bf2f(g.w);
    }
    if (i < end && half == 0) {          // single tail (lower half only)
        int v = csr[i];
        ushort4 g = *(const ushort4*)(XbfP + (size_t)v * HID + fl);
        a1x += bf2f(g.x); a1y += bf2f(g.y); a1z += bf2f(g.z); a1w += bf2f(g.w);
    }

    float tx = (a0x + a1x) + (a2x + a3x);
    float ty = (a0y + a1y) + (a2y + a3y);
    float tz = (a0z + a1z) + (a2z + a3z);
    float tw = (a0w + a1w) + (a2w + a3w);
    tx += __shfl_xor(tx, 32, 64);
    ty += __shfl_xor(ty, 32, 64);
    tz += __shfl_xor(tz, 32, 64);
    tw += __shfl_xor(tw, 32, 64);

    if (half == 0) {
        const size_t off = (size_t)node * HID + fl;
        float4 xv = *(const float4*)(Xf + off);
        float4 yv = *(const float4*)(Y + off);
        float d = degf[node];
        float y0 = yv.x - HSTEP * (d * xv.x - tx);
        float y1 = yv.y - HSTEP * (d * xv.y - ty);
        float y2 = yv.z - HSTEP * (d * xv.z - tz);
        float y3 = yv.w - HSTEP * (d * xv.w - tw);
        *(float4*)(Y + off) = make_float4(y0, y1, y2, y3);
        float x0 = xv.x + HSTEP * y0;
        float x1 = xv.y + HSTEP * y1;
        float x2 = xv.z + HSTEP * y2;
        float x3 = xv.w + HSTEP * y3;
        *(float4*)(Xf + off) = make_float4(x0, x1, x2, x3);
        ushort4 ub; ub.x = f2bf(x0); ub.y = f2bf(x1); ub.z = f2bf(x2); ub.w = f2bf(x3);
        *(ushort4*)(XbfN + off) = ub;
    }
}

// ---------------------------------------------------------------------------
// Backward MFMA LSTM (single cell, zero state). KK=128.
// ---------------------------------------------------------------------------
__global__ __launch_bounds__(512) void lstm_bwd_kernel(
    const u16* __restrict__ Xbf, u16* __restrict__ hbf_out,
    const u16* __restrict__ Wswz,
    const float* __restrict__ bih, const float* __restrict__ bhh)
{
    const int w = threadIdx.x >> 6;
    const int l = threadIdx.x & 63;
    const int l15 = l & 15, quad = l >> 4;
    const int m0 = blockIdx.x * 32;
    const int kof = quad * 8;

    f32x4 acc[2][4] = {};
    const size_t rowA0 = (size_t)(m0 + l15) * HID + kof;
    const size_t rowA1 = (size_t)(m0 + 16 + l15) * HID + kof;

    #pragma unroll
    for (int kc = 0; kc < 128; kc += 32) {
        const int ck = kc >> 5;
        short8 a0 = *(const short8*)(Xbf + rowA0 + kc);
        short8 a1 = *(const short8*)(Xbf + rowA1 + kc);
        #pragma unroll
        for (int q = 0; q < 4; ++q) {
            int nt = q * 8 + w;
            short8 b = *(const short8*)(Wswz + (((size_t)(nt * 4 + ck)) << 9) + (l << 3));
            acc[0][q] = __builtin_amdgcn_mfma_f32_16x16x32_bf16(a0, b, acc[0][q], 0, 0, 0);
            acc[1][q] = __builtin_amdgcn_mfma_f32_16x16x32_bf16(a1, b, acc[1][q], 0, 0, 0);
        }
    }

    const int j = w * 16 + l15;
    const float bI = bih[j]       + bhh[j];
    const float bG = bih[256 + j] + bhh[256 + j];
    const float bO = bih[384 + j] + bhh[384 + j];
    #pragma unroll
    for (int mt = 0; mt < 2; ++mt) {
        #pragma unroll
        for (int i = 0; i < 4; ++i) {
            int m = m0 + mt * 16 + quad * 4 + i;
            size_t off = (size_t)m * HID + j;
            float gi = sigm(acc[mt][0][i] + bI);
            float gg = tanh_fast(acc[mt][2][i] + bG);
            float go = sigm(acc[mt][3][i] + bO);
            hbf_out[off] = f2bf(go * tanh_fast(gi * gg));
        }
    }
}

// ---------------------------------------------------------------------------
// fc1 MFMA: F1bf = bf16(relu([hbf|hbbf] @ Wf1^T + bf1)).
// ---------------------------------------------------------------------------
__global__ __launch_bounds__(512) void fc1_mfma_kernel(
    const u16* __restrict__ hbf, const u16* __restrict__ hbbf,
    const u16* __restrict__ WswzH, const float* __restrict__ bias,
    u16* __restrict__ F1bf)
{
    const int w = threadIdx.x >> 6;
    const int l = threadIdx.x & 63;
    const int l15 = l & 15, quad = l >> 4;
    const int m0 = blockIdx.x * 32;
    const int kof = quad * 8;

    f32x4 acc[2] = {};
    #pragma unroll
    for (int kc = 0; kc < 256; kc += 32) {
        const int ck = kc >> 5;
        const u16* Ab = (kc >= 128) ? hbbf : hbf;
        int kl = (kc >= 128) ? (kc - 128) : kc;
        short8 a0 = *(const short8*)(Ab + (size_t)(m0 + l15) * HID + kl + kof);
        short8 a1 = *(const short8*)(Ab + (size_t)(m0 + 16 + l15) * HID + kl + kof);
        short8 b = *(const short8*)(WswzH + (((size_t)(w * 8 + ck)) << 9) + (l << 3));
        acc[0] = __builtin_amdgcn_mfma_f32_16x16x32_bf16(a0, b, acc[0], 0, 0, 0);
        acc[1] = __builtin_amdgcn_mfma_f32_16x16x32_bf16(a1, b, acc[1], 0, 0, 0);
    }
    const int j = w * 16 + l15;
    const float bj = bias[j];
    #pragma unroll
    for (int mt = 0; mt < 2; ++mt) {
        #pragma unroll
        for (int i = 0; i < 4; ++i) {
            int m = m0 + mt * 16 + quad * 4 + i;
            F1bf[(size_t)m * HID + j] = f2bf(fmaxf(acc[mt][i] + bj, 0.f));
        }
    }
}

// ---------------------------------------------------------------------------
// fc2 MFMA: out = F1bf @ Wf2^T + bf2, N=64. 256 threads / 4 waves (wave = n-tile).
// ---------------------------------------------------------------------------
__global__ __launch_bounds__(256) void fc2_mfma_kernel(
    const u16* __restrict__ F1bf, const u16* __restrict__ WswzO,
    const float* __restrict__ bias, void* __restrict__ out,
    const int* __restrict__ oflag)
{
    const int w = threadIdx.x >> 6;        // n-tile 0..3
    const int l = threadIdx.x & 63;
    const int l15 = l & 15, quad = l >> 4;
    const int m0 = blockIdx.x * 32;
    const int kof = quad * 8;

    f32x4 acc[2] = {};
    #pragma unroll
    for (int kc = 0; kc < 128; kc += 32) {
        const int ck = kc >> 5;
        short8 a0 = *(const short8*)(F1bf + (size_t)(m0 + l15) * HID + kc + kof);
        short8 a1 = *(const short8*)(F1bf + (size_t)(m0 + 16 + l15) * HID + kc + kof);
        short8 b = *(const short8*)(WswzO + (((size_t)(w * 4 + ck)) << 9) + (l << 3));
        acc[0] = __builtin_amdgcn_mfma_f32_16x16x32_bf16(a0, b, acc[0], 0, 0, 0);
        acc[1] = __builtin_amdgcn_mfma_f32_16x16x32_bf16(a1, b, acc[1], 0, 0, 0);
    }
    const int j = w * 16 + l15;
    const float bj = bias[j];
    const bool obf = (*oflag == 0);
    #pragma unroll
    for (int mt = 0; mt < 2; ++mt) {
        #pragma unroll
        for (int i = 0; i < 4; ++i) {
            int m = m0 + mt * 16 + quad * 4 + i;
            float o = acc[mt][i] + bj;
            if (obf) ((u16*)out)[(size_t)m * OUT_DIM + j] = f2bf(o);
            else     ((float*)out)[(size_t)m * OUT_DIM + j] = o;
        }
    }
}

// ---------------------------------------------------------------------------
extern "C" void kernel_launch(void* const* d_in, const int* in_sizes, int n_in,
                              void* d_out, int out_size, void* d_ws, size_t ws_size,
                              hipStream_t stream)
{
    const void* x  = d_in[0];
    const int*  ei = (const int*)d_in[1];

    const size_t SZ_NH  = (size_t)N_NODES * HID * sizeof(float);   // 10,240,000
    const size_t SZ_NHB = (size_t)N_NODES * HID * sizeof(u16);     //  5,120,000
    const size_t SZ_I   = 80128;

    char* p = (char*)d_ws;
    float* Xa    = (float*)p; p += SZ_NH;
    float* Xb    = (float*)p; p += SZ_NH;      // H1 scratch, later F1bf
    float* Y     = (float*)p; p += SZ_NH;
    float* cf    = (float*)p; p += SZ_NH;
    u16*   hbf   = (u16*)p;   p += SZ_NHB;
    u16*   XbfA  = (u16*)p;   p += SZ_NHB;
    u16*   XbfB  = (u16*)p;   p += SZ_NHB;
    int*   deg   = (int*)p;   p += SZ_I;
    int*   fill  = (int*)p;   p += SZ_I;
    int*   rowp  = (int*)p;   p += SZ_I;
    float* degf  = (float*)p; p += SZ_I;
    int*   csr   = (int*)p;   p += (size_t)N_EDGES * sizeof(int);
    int*   flag  = (int*)p;   p += 128;
    float* wsf   = (float*)p; p += 272832 * sizeof(float);
    u16*   WswzF = (u16*)p;   p += 131072 * sizeof(u16);
    u16*   WswzB = (u16*)p;   p += 65536 * sizeof(u16);
    u16*   WswzH = (u16*)p;   p += 32768 * sizeof(u16);
    u16*   WswzO = (u16*)p;   p += 8192 * sizeof(u16);

    // converted f32 weight sub-pointers (offsets match cvt_off)
    float* Wenc1 = wsf + 0;
    float* benc1 = wsf + 16384;
    float* Wenc2 = wsf + 16512;
    float* benc2 = wsf + 32896;
    float* bihf  = wsf + 164096;
    float* bhhf  = wsf + 164608;
    float* bihb  = wsf + 230656;
    float* bhhb  = wsf + 231168;
    float* bf1   = wsf + 264448;
    float* bf2_  = wsf + 272768;

    float* H1   = Xb;        // encoder intermediate
    u16*   hbbf = (u16*)Y;   // backward h bf16; Y dead after last wave step
    u16*   F1bf = (u16*)Xb;  // head intermediate; H1 long dead

    hipMemsetAsync(Y, 0, 2 * SZ_NH + SZ_NHB, stream);   // Y, cf, hbf (contiguous)
    hipMemsetAsync(deg, 0, 2 * SZ_I, stream);           // deg, fill (contiguous)

    // dtype detect + weight conversion (f32 master, swizzled bf16 MFMA copies)
    detect_kernel<<<1, 256, 0, stream>>>((const u16*)x, flag);
    CvtArgs ca;
    ca.s[0] = d_in[2];  ca.s[1] = d_in[3];  ca.s[2] = d_in[4];  ca.s[3] = d_in[5];
    ca.s[4] = d_in[6];  ca.s[5] = d_in[7];  ca.s[6] = d_in[8];  ca.s[7] = d_in[9];
    ca.s[8] = d_in[10]; ca.s[9] = d_in[12]; ca.s[10] = d_in[13];
    ca.s[11] = d_in[14]; ca.s[12] = d_in[15]; ca.s[13] = d_in[16]; ca.s[14] = d_in[17];
    convert_kernel<<<(272832 + 255) / 256, 256, 0, stream>>>(ca, wsf, flag);
    build_wswz_kernel<<<512, 256, 0, stream>>>(wsf, WswzF, WswzB, WswzH, WswzO);

    // CSR build
    count_kernel<<<(N_EDGES + 255) / 256, 256, 0, stream>>>(ei, deg);
    scan_kernel<<<1, 1024, 0, stream>>>(deg, rowp, degf);
    fill_kernel<<<(N_EDGES + 255) / 256, 256, 0, stream>>>(ei, rowp, fill, csr);

    const int MB = (N_NODES + 63) / 64;   // 313
    const int NB = N_NODES / 32;          // 625

    // encoder: H1 = relu(x @ Wenc1^T + b1); Xa = H1 @ Wenc2^T + b2 (+ bf16 copy)
    gemm_kernel<true, false><<<dim3(MB, 2), 256, 0, stream>>>(
        x, Wenc1, benc1, H1, nullptr, N_NODES, HID, HID, flag);
    gemm_kernel<false, true><<<dim3(MB, 2), 256, 0, stream>>>(
        H1, Wenc2, benc2, Xa, XbfA, N_NODES, HID, HID, nullptr);

    // t=0 LSTM, then 15 x (wave -> LSTM)
    lstm_fwd_kernel<<<NB, 512, 0, stream>>>(XbfA, hbf, cf, WswzF, bihf, bhhf);
    u16* XbP = XbfA;
    u16* XbN = XbfB;
    for (int t = 1; t < NSTEPS; ++t) {
        wave_kernel<<<N_NODES / 4, 256, 0, stream>>>(
            Xa, XbP, XbN, Y, degf, rowp, csr);
        u16* tmp = XbP; XbP = XbN; XbN = tmp;
        lstm_fwd_kernel<<<NB, 512, 0, stream>>>(XbP, hbf, cf, WswzF, bihf, bhhf);
    }

    // backward LSTM: only hs_b[0] used -> one cell on X_tilde[15], zero state
    lstm_bwd_kernel<<<NB, 512, 0, stream>>>(XbP, hbbf, WswzB, bihb, bhhb);

    // head: F1bf = bf16(relu([hbf|hbbf] @ Wf1^T + bf1)); out = F1bf @ Wf2^T + bf2
    fc1_mfma_kernel<<<NB, 512, 0, stream>>>(hbf, hbbf, WswzH, bf1, F1bf);
    fc2_mfma_kernel<<<NB, 256, 0, stream>>>(F1bf, WswzO, bf2_, d_out, flag);
}

// Round 13
// 996.586 us; speedup vs baseline: 1.4121x; 1.0242x over previous
//
#include <hip/hip_runtime.h>
#include <hip/hip_bf16.h>
#include <cstdint>
#include <cstddef>

#define N_NODES 20000
#define N_EDGES 640000
#define HID     128
#define OUT_DIM 64
#define NSTEPS  16
#define HSTEP   0.1f

typedef unsigned short u16;
typedef __attribute__((ext_vector_type(8))) short short8;   // 8 bf16 (4 VGPRs)
typedef __attribute__((ext_vector_type(4))) float f32x4;    // MFMA C/D

__device__ __forceinline__ float bf2f(u16 u) {
    union { unsigned int i; float f; } v; v.i = ((unsigned int)u) << 16; return v.f;
}
__device__ __forceinline__ u16 f2bf(float f) {
    union { float f; unsigned int i; } v; v.f = f;
    unsigned int x = v.i;
    unsigned int r = x + 0x7FFFu + ((x >> 16) & 1u);   // round-to-nearest-even
    return (u16)(r >> 16);
}

__device__ __forceinline__ float sigm(float x) { return 1.f / (1.f + __expf(-x)); }
__device__ __forceinline__ float tanh_fast(float x) {
    float e2 = __expf(-2.f * fabsf(x));
    float t = (1.f - e2) / (1.f + e2);
    return copysignf(t, x);
}

// ---------------------------------------------------------------------------
// Storage-dtype detection. flag=1 -> tensors stored as f32; flag=0 -> bf16.
// ---------------------------------------------------------------------------
__global__ void detect_kernel(const u16* __restrict__ xraw, int* __restrict__ flag) {
    __shared__ int cnt;
    if (threadIdx.x == 0) cnt = 0;
    __syncthreads();
    int c = 0;
    for (int i = threadIdx.x; i < 4096; i += 256) {
        int e = (xraw[i] >> 7) & 0xFF;
        if (e >= 0x90) c++;
    }
    atomicAdd(&cnt, c);
    __syncthreads();
    if (threadIdx.x == 0) *flag = (cnt > 100) ? 1 : 0;
}

// ---------------------------------------------------------------------------
// Packed conversion of the 15 weight/bias tensors into contiguous f32 ws.
// ---------------------------------------------------------------------------
#define N_CVT 15
struct CvtArgs { const void* s[N_CVT]; };
__constant__ const int cvt_off[N_CVT + 1] = {
    0, 16384, 16512, 32896, 33024, 98560, 164096, 164608, 165120,
    230656, 231168, 231680, 264448, 264576, 272768, 272832 };

__global__ void convert_kernel(CvtArgs a, float* __restrict__ dst,
                               const int* __restrict__ flag) {
    int i = blockIdx.x * blockDim.x + threadIdx.x;
    if (i >= 272832) return;
    int seg = 0;
    #pragma unroll
    for (int s = 1; s < N_CVT; ++s) if (i >= cvt_off[s]) seg = s;
    int j = i - cvt_off[seg];
    float v = (*flag) ? ((const float*)a.s[seg])[j]
                      : bf2f(((const u16*)a.s[seg])[j]);
    dst[i] = v;
}

// ---------------------------------------------------------------------------
// Build bf16 weights in MFMA B-fragment-swizzled order.
// elem (nt, ck, lane, j) = W[nt*16 + (lane&15)][ck*32 + (lane>>4)*8 + j]
// flat o = ((nt*NCK + ck)*64 + lane)*8 + j.
// ---------------------------------------------------------------------------
__global__ void build_wswz_kernel(const float* __restrict__ wsf,
                                  u16* __restrict__ WswzF, u16* __restrict__ WswzB,
                                  u16* __restrict__ WswzH, u16* __restrict__ WswzO,
                                  u16* __restrict__ WswzE1, u16* __restrict__ WswzE2) {
    int o = blockIdx.x * blockDim.x + threadIdx.x;
    if (o < 131072) {   // forward [Wihf|Whhf], NCK=8
        int j = o & 7, l = (o >> 3) & 63, rest = o >> 9;
        int ck = rest & 7, nt = rest >> 3;
        int n = nt * 16 + (l & 15);
        int k = ck * 32 + (l >> 4) * 8 + j;
        const float* Wihf = wsf + 33024;
        const float* Whhf = wsf + 98560;
        float v = (k < 128) ? Wihf[n * 128 + k] : Whhf[n * 128 + (k - 128)];
        WswzF[o] = f2bf(v);
    }
    if (o < 65536) {    // backward Wihb, NCK=4
        int j = o & 7, l = (o >> 3) & 63, rest = o >> 9;
        int ck = rest & 3, nt = rest >> 2;
        int n = nt * 16 + (l & 15);
        int k = ck * 32 + (l >> 4) * 8 + j;
        const float* Wihb = wsf + 165120;
        WswzB[o] = f2bf(Wihb[n * 128 + k]);
    }
    if (o < 32768) {    // fc1 Wf1 [128][256], NCK=8
        int j = o & 7, l = (o >> 3) & 63, rest = o >> 9;
        int ck = rest & 7, nt = rest >> 3;
        int n = nt * 16 + (l & 15);
        int k = ck * 32 + (l >> 4) * 8 + j;
        const float* Wf1 = wsf + 231680;
        WswzH[o] = f2bf(Wf1[n * 256 + k]);
    }
    if (o < 8192) {     // fc2 Wf2 [64][128], NCK=4
        int j = o & 7, l = (o >> 3) & 63, rest = o >> 9;
        int ck = rest & 3, nt = rest >> 2;
        int n = nt * 16 + (l & 15);
        int k = ck * 32 + (l >> 4) * 8 + j;
        const float* Wf2 = wsf + 264576;
        WswzO[o] = f2bf(Wf2[n * 128 + k]);
    }
    if (o < 16384) {    // enc1 Wenc1 [128][128], NCK=4, and enc2 Wenc2
        int j = o & 7, l = (o >> 3) & 63, rest = o >> 9;
        int ck = rest & 3, nt = rest >> 2;
        int n = nt * 16 + (l & 15);
        int k = ck * 32 + (l >> 4) * 8 + j;
        const float* We1 = wsf + 0;
        const float* We2 = wsf + 16512;
        WswzE1[o] = f2bf(We1[n * 128 + k]);
        WswzE2[o] = f2bf(We2[n * 128 + k]);
    }
}

// ---------------------------------------------------------------------------
// CSR build: degree count -> exclusive scan -> bucket fill
// ---------------------------------------------------------------------------
__global__ void count_kernel(const int* __restrict__ ei, int* __restrict__ deg) {
    int e = blockIdx.x * blockDim.x + threadIdx.x;
    if (e < N_EDGES) atomicAdd(&deg[ei[N_EDGES + e]], 1);
}

__global__ __launch_bounds__(1024) void scan_kernel(const int* __restrict__ deg,
                                                    int* __restrict__ rowptr,
                                                    float* __restrict__ degf) {
    __shared__ int sd[1024];
    const int t = threadIdx.x;
    const int CH = (N_NODES + 1023) / 1024;   // 20
    int base = t * CH;
    int s = 0;
    for (int i = 0; i < CH; ++i) {
        int idx = base + i;
        if (idx < N_NODES) s += deg[idx];
    }
    sd[t] = s;
    __syncthreads();
    for (int off = 1; off < 1024; off <<= 1) {
        int v = (t >= off) ? sd[t - off] : 0;
        __syncthreads();
        sd[t] += v;
        __syncthreads();
    }
    int run = (t == 0) ? 0 : sd[t - 1];
    for (int i = 0; i < CH; ++i) {
        int idx = base + i;
        if (idx < N_NODES) {
            rowptr[idx] = run;
            degf[idx] = (float)deg[idx];
            run += deg[idx];
        }
    }
    if (t == 1023) rowptr[N_NODES] = sd[1023];
}

__global__ void fill_kernel(const int* __restrict__ ei, const int* __restrict__ rowptr,
                            int* __restrict__ fill, int* __restrict__ csr) {
    int e = blockIdx.x * blockDim.x + threadIdx.x;
    if (e < N_EDGES) {
        int d = ei[N_EDGES + e];
        int p = atomicAdd(&fill[d], 1);
        csr[rowptr[d] + p] = ei[e];
    }
}

// ---------------------------------------------------------------------------
// Fused encoder (one dispatch): per 32-row tile,
//   enc1: H1 = relu(x @ Wenc1^T + b1)  (x cast to bf16 inline per flag)
//   -> H1 bf16 in LDS (row-local chain) ->
//   enc2: X0 = H1 @ Wenc2^T + b2  -> Xa f32 + XbfA bf16.
// 512 threads / 8 waves; wave w = n-tile w (N=128).
// ---------------------------------------------------------------------------
__global__ __launch_bounds__(512) void encoder_kernel(
    const void* __restrict__ xv,
    const u16* __restrict__ WswzE1, const u16* __restrict__ WswzE2,
    const float* __restrict__ benc1, const float* __restrict__ benc2,
    float* __restrict__ Xa, u16* __restrict__ XbfA, const int* __restrict__ flag)
{
    __shared__ __align__(16) u16 H1[32][136];   // row stride 272B: 16B-aligned rows
    const int w = threadIdx.x >> 6;
    const int l = threadIdx.x & 63;
    const int l15 = l & 15, quad = l >> 4;
    const int m0 = blockIdx.x * 32;
    const int kof = quad * 8;
    const int j = w * 16 + l15;
    const bool xf32 = (*flag != 0);

    // ---- enc1 ----
    f32x4 acc[2] = {};
    #pragma unroll
    for (int ck = 0; ck < 4; ++ck) {
        const int kc = ck * 32;
        short8 a0, a1;
        if (xf32) {
            const float* r0 = (const float*)xv + (size_t)(m0 + l15) * HID + kc + kof;
            const float* r1 = (const float*)xv + (size_t)(m0 + 16 + l15) * HID + kc + kof;
            union { u16 u[8]; short8 v; } t0, t1;
            #pragma unroll
            for (int e = 0; e < 8; ++e) { t0.u[e] = f2bf(r0[e]); t1.u[e] = f2bf(r1[e]); }
            a0 = t0.v; a1 = t1.v;
        } else {
            a0 = *(const short8*)((const u16*)xv + (size_t)(m0 + l15) * HID + kc + kof);
            a1 = *(const short8*)((const u16*)xv + (size_t)(m0 + 16 + l15) * HID + kc + kof);
        }
        short8 b = *(const short8*)(WswzE1 + (((size_t)(w * 4 + ck)) << 9) + (l << 3));
        acc[0] = __builtin_amdgcn_mfma_f32_16x16x32_bf16(a0, b, acc[0], 0, 0, 0);
        acc[1] = __builtin_amdgcn_mfma_f32_16x16x32_bf16(a1, b, acc[1], 0, 0, 0);
    }
    {
        const float bj = benc1[j];
        #pragma unroll
        for (int mt = 0; mt < 2; ++mt)
            #pragma unroll
            for (int i = 0; i < 4; ++i)
                H1[mt * 16 + quad * 4 + i][j] = f2bf(fmaxf(acc[mt][i] + bj, 0.f));
    }
    __syncthreads();

    // ---- enc2 ----
    f32x4 acc2[2] = {};
    #pragma unroll
    for (int ck = 0; ck < 4; ++ck) {
        const int kc = ck * 32;
        short8 a0 = *(const short8*)(&H1[l15][kc + kof]);
        short8 a1 = *(const short8*)(&H1[16 + l15][kc + kof]);
        short8 b = *(const short8*)(WswzE2 + (((size_t)(w * 4 + ck)) << 9) + (l << 3));
        acc2[0] = __builtin_amdgcn_mfma_f32_16x16x32_bf16(a0, b, acc2[0], 0, 0, 0);
        acc2[1] = __builtin_amdgcn_mfma_f32_16x16x32_bf16(a1, b, acc2[1], 0, 0, 0);
    }
    {
        const float bj = benc2[j];
        #pragma unroll
        for (int mt = 0; mt < 2; ++mt)
            #pragma unroll
            for (int i = 0; i < 4; ++i) {
                int m = m0 + mt * 16 + quad * 4 + i;
                float o = acc2[mt][i] + bj;
                Xa[(size_t)m * HID + j] = o;
                XbfA[(size_t)m * HID + j] = f2bf(o);
            }
    }
}

// ---------------------------------------------------------------------------
// Forward MFMA LSTM step (proven r11 body). 512 threads / 8 waves, 32 rows.
// Wave w owns cols q*128 + w*16 + [0,16); B from WswzF (coalesced frag order).
// h/c updated in place (own rows only).
// ---------------------------------------------------------------------------
__global__ __launch_bounds__(512) void lstm_fwd_kernel(
    const u16* __restrict__ Xbf, u16* hbf, float* cf,
    const u16* __restrict__ Wswz,
    const float* __restrict__ bih, const float* __restrict__ bhh)
{
    const int w = threadIdx.x >> 6;
    const int l = threadIdx.x & 63;
    const int l15 = l & 15, quad = l >> 4;
    const int m0 = blockIdx.x * 32;
    const int kof = quad * 8;

    f32x4 acc[2][4] = {};
    const size_t rowA0 = (size_t)(m0 + l15) * HID + kof;
    const size_t rowA1 = (size_t)(m0 + 16 + l15) * HID + kof;

    #pragma unroll
    for (int kc = 0; kc < 256; kc += 32) {
        const int ck = kc >> 5;
        const u16* Ab = (kc >= 128) ? hbf : Xbf;
        int kl = (kc >= 128) ? (kc - 128) : kc;
        short8 a0 = *(const short8*)(Ab + rowA0 + kl);
        short8 a1 = *(const short8*)(Ab + rowA1 + kl);
        #pragma unroll
        for (int q = 0; q < 4; ++q) {
            int nt = q * 8 + w;
            short8 b = *(const short8*)(Wswz + (((size_t)(nt * 8 + ck)) << 9) + (l << 3));
            acc[0][q] = __builtin_amdgcn_mfma_f32_16x16x32_bf16(a0, b, acc[0][q], 0, 0, 0);
            acc[1][q] = __builtin_amdgcn_mfma_f32_16x16x32_bf16(a1, b, acc[1][q], 0, 0, 0);
        }
    }

    const int j = w * 16 + l15;
    const float bI = bih[j]       + bhh[j];
    const float bF = bih[128 + j] + bhh[128 + j];
    const float bG = bih[256 + j] + bhh[256 + j];
    const float bO = bih[384 + j] + bhh[384 + j];
    #pragma unroll
    for (int mt = 0; mt < 2; ++mt) {
        #pragma unroll
        for (int i = 0; i < 4; ++i) {
            int m = m0 + mt * 16 + quad * 4 + i;
            size_t off = (size_t)m * HID + j;
            float gi = sigm(acc[mt][0][i] + bI);
            float gf = sigm(acc[mt][1][i] + bF);
            float gg = tanh_fast(acc[mt][2][i] + bG);
            float go = sigm(acc[mt][3][i] + bO);
            float cn = gf * cf[off] + gi * gg;
            cf[off] = cn;
            hbf[off] = f2bf(go * tanh_fast(cn));
        }
    }
}

// ---------------------------------------------------------------------------
// Wave step (proven r11 body): one node per wave; paired-edge gather (lanes
// 0-31 edge A, 32-63 edge B, ushort4/lane), 4-pair unroll -> 8 edges in
// flight. Cross-half __shfl_xor merge. f32 X/Y in place; bf16 snapshot out.
// ---------------------------------------------------------------------------
__global__ __launch_bounds__(256) void wave_kernel(
    float* __restrict__ Xf, const u16* __restrict__ XbfP, u16* __restrict__ XbfN,
    float* __restrict__ Y, const float* __restrict__ degf,
    const int* __restrict__ rowptr, const int* __restrict__ csr)
{
    const int node = blockIdx.x * 4 + (threadIdx.x >> 6);
    const int lane = threadIdx.x & 63;
    const int half = lane >> 5;
    const int fl = (lane & 31) * 4;

    const int beg = rowptr[node], end = rowptr[node + 1];
    float a0x = 0.f, a0y = 0.f, a0z = 0.f, a0w = 0.f;
    float a1x = 0.f, a1y = 0.f, a1z = 0.f, a1w = 0.f;
    float a2x = 0.f, a2y = 0.f, a2z = 0.f, a2w = 0.f;
    float a3x = 0.f, a3y = 0.f, a3z = 0.f, a3w = 0.f;

    int i = beg;
    for (; i + 8 <= end; i += 8) {
        int v0 = csr[i + 0 + half];
        int v1 = csr[i + 2 + half];
        int v2 = csr[i + 4 + half];
        int v3 = csr[i + 6 + half];
        ushort4 g0 = *(const ushort4*)(XbfP + (size_t)v0 * HID + fl);
        ushort4 g1 = *(const ushort4*)(XbfP + (size_t)v1 * HID + fl);
        ushort4 g2 = *(const ushort4*)(XbfP + (size_t)v2 * HID + fl);
        ushort4 g3 = *(const ushort4*)(XbfP + (size_t)v3 * HID + fl);
        a0x += bf2f(g0.x); a0y += bf2f(g0.y); a0z += bf2f(g0.z); a0w += bf2f(g0.w);
        a1x += bf2f(g1.x); a1y += bf2f(g1.y); a1z += bf2f(g1.z); a1w += bf2f(g1.w);
        a2x += bf2f(g2.x); a2y += bf2f(g2.y); a2z += bf2f(g2.z); a2w += bf2f(g2.w);
        a3x += bf2f(g3.x); a3y += bf2f(g3.y); a3z += bf2f(g3.z); a3w += bf2f(g3.w);
    }
    for (; i + 2 <= end; i += 2) {
        int v = csr[i + half];
        ushort4 g = *(const ushort4*)(XbfP + (size_t)v * HID + fl);
        a0x += bf2f(g.x); a0y += bf2f(g.y); a0z += bf2f(g.z); a0w += bf2f(g.w);
    }
    if (i < end && half == 0) {
        int v = csr[i];
        ushort4 g = *(const ushort4*)(XbfP + (size_t)v * HID + fl);
        a1x += bf2f(g.x); a1y += bf2f(g.y); a1z += bf2f(g.z); a1w += bf2f(g.w);
    }

    float tx = (a0x + a1x) + (a2x + a3x);
    float ty = (a0y + a1y) + (a2y + a3y);
    float tz = (a0z + a1z) + (a2z + a3z);
    float tw = (a0w + a1w) + (a2w + a3w);
    tx += __shfl_xor(tx, 32, 64);
    ty += __shfl_xor(ty, 32, 64);
    tz += __shfl_xor(tz, 32, 64);
    tw += __shfl_xor(tw, 32, 64);

    if (half == 0) {
        const size_t off = (size_t)node * HID + fl;
        float4 xv = *(const float4*)(Xf + off);
        float4 yv = *(const float4*)(Y + off);
        float d = degf[node];
        float y0 = yv.x - HSTEP * (d * xv.x - tx);
        float y1 = yv.y - HSTEP * (d * xv.y - ty);
        float y2 = yv.z - HSTEP * (d * xv.z - tz);
        float y3 = yv.w - HSTEP * (d * xv.w - tw);
        *(float4*)(Y + off) = make_float4(y0, y1, y2, y3);
        float x0 = xv.x + HSTEP * y0;
        float x1 = xv.y + HSTEP * y1;
        float x2 = xv.z + HSTEP * y2;
        float x3 = xv.w + HSTEP * y3;
        *(float4*)(Xf + off) = make_float4(x0, x1, x2, x3);
        ushort4 ub; ub.x = f2bf(x0); ub.y = f2bf(x1); ub.z = f2bf(x2); ub.w = f2bf(x3);
        *(ushort4*)(XbfN + off) = ub;
    }
}

// ---------------------------------------------------------------------------
// Fused tail (one dispatch): per 32-row tile,
//   phase 1: backward cell (zero state) on X_tilde[15] -> Hb (LDS)
//   phase 2: fc1 = relu([hbf | Hb] @ Wf1^T + bf1)      -> F1 (LDS)
//   phase 3: fc2 = F1 @ Wf2^T + bf2                    -> d_out
// Strictly tile-local chain; __syncthreads between phases.
// ---------------------------------------------------------------------------
__global__ __launch_bounds__(512) void tail_kernel(
    const u16* __restrict__ Xbf, const u16* __restrict__ hbf,
    const u16* __restrict__ WswzB, const u16* __restrict__ WswzH,
    const u16* __restrict__ WswzO,
    const float* __restrict__ bihb, const float* __restrict__ bhhb,
    const float* __restrict__ bf1, const float* __restrict__ bf2_,
    void* __restrict__ out, const int* __restrict__ oflag)
{
    __shared__ __align__(16) u16 Hb[32][136];
    __shared__ __align__(16) u16 F1[32][136];
    const int w = threadIdx.x >> 6;
    const int l = threadIdx.x & 63;
    const int l15 = l & 15, quad = l >> 4;
    const int m0 = blockIdx.x * 32;
    const int kof = quad * 8;
    const int j = w * 16 + l15;

    // ---- phase 1: backward cell -> Hb ----
    {
        f32x4 acc[2][4] = {};
        const size_t rowA0 = (size_t)(m0 + l15) * HID + kof;
        const size_t rowA1 = (size_t)(m0 + 16 + l15) * HID + kof;
        #pragma unroll
        for (int kc = 0; kc < 128; kc += 32) {
            const int ck = kc >> 5;
            short8 a0 = *(const short8*)(Xbf + rowA0 + kc);
            short8 a1 = *(const short8*)(Xbf + rowA1 + kc);
            #pragma unroll
            for (int q = 0; q < 4; ++q) {
                int nt = q * 8 + w;
                short8 b = *(const short8*)(WswzB + (((size_t)(nt * 4 + ck)) << 9) + (l << 3));
                acc[0][q] = __builtin_amdgcn_mfma_f32_16x16x32_bf16(a0, b, acc[0][q], 0, 0, 0);
                acc[1][q] = __builtin_amdgcn_mfma_f32_16x16x32_bf16(a1, b, acc[1][q], 0, 0, 0);
            }
        }
        const float bI = bihb[j]       + bhhb[j];
        const float bG = bihb[256 + j] + bhhb[256 + j];
        const float bO = bihb[384 + j] + bhhb[384 + j];
        #pragma unroll
        for (int mt = 0; mt < 2; ++mt)
            #pragma unroll
            for (int i = 0; i < 4; ++i) {
                float gi = sigm(acc[mt][0][i] + bI);
                float gg = tanh_fast(acc[mt][2][i] + bG);
                float go = sigm(acc[mt][3][i] + bO);
                Hb[mt * 16 + quad * 4 + i][j] = f2bf(go * tanh_fast(gi * gg));
            }
    }
    __syncthreads();

    // ---- phase 2: fc1 -> F1 ----
    {
        f32x4 acc[2] = {};
        #pragma unroll
        for (int kc = 0; kc < 256; kc += 32) {
            const int ck = kc >> 5;
            short8 a0, a1;
            if (kc < 128) {
                a0 = *(const short8*)(hbf + (size_t)(m0 + l15) * HID + kc + kof);
                a1 = *(const short8*)(hbf + (size_t)(m0 + 16 + l15) * HID + kc + kof);
            } else {
                a0 = *(const short8*)(&Hb[l15][(kc - 128) + kof]);
                a1 = *(const short8*)(&Hb[16 + l15][(kc - 128) + kof]);
            }
            short8 b = *(const short8*)(WswzH + (((size_t)(w * 8 + ck)) << 9) + (l << 3));
            acc[0] = __builtin_amdgcn_mfma_f32_16x16x32_bf16(a0, b, acc[0], 0, 0, 0);
            acc[1] = __builtin_amdgcn_mfma_f32_16x16x32_bf16(a1, b, acc[1], 0, 0, 0);
        }
        const float bj = bf1[j];
        #pragma unroll
        for (int mt = 0; mt < 2; ++mt)
            #pragma unroll
            for (int i = 0; i < 4; ++i)
                F1[mt * 16 + quad * 4 + i][j] = f2bf(fmaxf(acc[mt][i] + bj, 0.f));
    }
    __syncthreads();

    // ---- phase 3: fc2 -> out ----
    {
        const int nt = w & 3, mh = w >> 2;
        f32x4 acc = {};
        #pragma unroll
        for (int kc = 0; kc < 128; kc += 32) {
            const int ck = kc >> 5;
            short8 a = *(const short8*)(&F1[mh * 16 + l15][kc + kof]);
            short8 b = *(const short8*)(WswzO + (((size_t)(nt * 4 + ck)) << 9) + (l << 3));
            acc = __builtin_amdgcn_mfma_f32_16x16x32_bf16(a, b, acc, 0, 0, 0);
        }
        const int jo = nt * 16 + l15;
        const float bj = bf2_[jo];
        const bool obf = (*oflag == 0);
        #pragma unroll
        for (int i = 0; i < 4; ++i) {
            int m = m0 + mh * 16 + quad * 4 + i;
            float o = acc[i] + bj;
            if (obf) ((u16*)out)[(size_t)m * OUT_DIM + jo] = f2bf(o);
            else     ((float*)out)[(size_t)m * OUT_DIM + jo] = o;
        }
    }
}

// ---------------------------------------------------------------------------
extern "C" void kernel_launch(void* const* d_in, const int* in_sizes, int n_in,
                              void* d_out, int out_size, void* d_ws, size_t ws_size,
                              hipStream_t stream)
{
    const void* x  = d_in[0];
    const int*  ei = (const int*)d_in[1];

    const size_t SZ_NH  = (size_t)N_NODES * HID * sizeof(float);   // 10,240,000
    const size_t SZ_NHB = (size_t)N_NODES * HID * sizeof(u16);     //  5,120,000
    const size_t SZ_I   = 80128;

    char* p = (char*)d_ws;
    float* Xa    = (float*)p; p += SZ_NH;
    float* Y     = (float*)p; p += SZ_NH;
    float* cf    = (float*)p; p += SZ_NH;
    u16*   hbf   = (u16*)p;   p += SZ_NHB;
    u16*   XbfA  = (u16*)p;   p += SZ_NHB;
    u16*   XbfB  = (u16*)p;   p += SZ_NHB;
    int*   deg   = (int*)p;   p += SZ_I;
    int*   fill  = (int*)p;   p += SZ_I;
    int*   rowp  = (int*)p;   p += SZ_I;
    float* degf  = (float*)p; p += SZ_I;
    int*   csr   = (int*)p;   p += (size_t)N_EDGES * sizeof(int);
    int*   flag  = (int*)p;   p += 128;
    float* wsf   = (float*)p; p += 272832 * sizeof(float);
    u16*   WswzF  = (u16*)p;  p += 131072 * sizeof(u16);
    u16*   WswzB  = (u16*)p;  p += 65536 * sizeof(u16);
    u16*   WswzH  = (u16*)p;  p += 32768 * sizeof(u16);
    u16*   WswzO  = (u16*)p;  p += 8192 * sizeof(u16);
    u16*   WswzE1 = (u16*)p;  p += 16384 * sizeof(u16);
    u16*   WswzE2 = (u16*)p;  p += 16384 * sizeof(u16);

    // converted f32 weight sub-pointers (offsets match cvt_off)
    float* benc1 = wsf + 16384;
    float* benc2 = wsf + 32896;
    float* bihf  = wsf + 164096;
    float* bhhf  = wsf + 164608;
    float* bihb  = wsf + 230656;
    float* bhhb  = wsf + 231168;
    float* bf1   = wsf + 264448;
    float* bf2_  = wsf + 272768;

    hipMemsetAsync(Y, 0, 2 * SZ_NH + SZ_NHB, stream);   // Y, cf, hbf (contiguous)
    hipMemsetAsync(deg, 0, 2 * SZ_I, stream);           // deg, fill (contiguous)

    // dtype detect + weight conversion (f32 master, swizzled bf16 MFMA copies)
    detect_kernel<<<1, 256, 0, stream>>>((const u16*)x, flag);
    CvtArgs ca;
    ca.s[0] = d_in[2];  ca.s[1] = d_in[3];  ca.s[2] = d_in[4];  ca.s[3] = d_in[5];
    ca.s[4] = d_in[6];  ca.s[5] = d_in[7];  ca.s[6] = d_in[8];  ca.s[7] = d_in[9];
    ca.s[8] = d_in[10]; ca.s[9] = d_in[12]; ca.s[10] = d_in[13];
    ca.s[11] = d_in[14]; ca.s[12] = d_in[15]; ca.s[13] = d_in[16]; ca.s[14] = d_in[17];
    convert_kernel<<<(272832 + 255) / 256, 256, 0, stream>>>(ca, wsf, flag);
    build_wswz_kernel<<<512, 256, 0, stream>>>(wsf, WswzF, WswzB, WswzH, WswzO,
                                               WswzE1, WswzE2);

    // CSR build
    count_kernel<<<(N_EDGES + 255) / 256, 256, 0, stream>>>(ei, deg);
    scan_kernel<<<1, 1024, 0, stream>>>(deg, rowp, degf);
    fill_kernel<<<(N_EDGES + 255) / 256, 256, 0, stream>>>(ei, rowp, fill, csr);

    const int NB = N_NODES / 32;          // 625

    // fused encoder: x -> X0 (Xa f32 + XbfA bf16), one dispatch
    encoder_kernel<<<NB, 512, 0, stream>>>(x, WswzE1, WswzE2, benc1, benc2,
                                           Xa, XbfA, flag);

    // t=0 LSTM, then 15 x (wave -> LSTM)
    lstm_fwd_kernel<<<NB, 512, 0, stream>>>(XbfA, hbf, cf, WswzF, bihf, bhhf);
    u16* XbP = XbfA;
    u16* XbN = XbfB;
    for (int t = 1; t < NSTEPS; ++t) {
        wave_kernel<<<N_NODES / 4, 256, 0, stream>>>(
            Xa, XbP, XbN, Y, degf, rowp, csr);
        u16* tmp = XbP; XbP = XbN; XbN = tmp;
        lstm_fwd_kernel<<<NB, 512, 0, stream>>>(XbP, hbf, cf, WswzF, bihf, bhhf);
    }

    // fused tail: backward cell + fc1 + fc2, one dispatch
    tail_kernel<<<NB, 512, 0, stream>>>(XbP, hbf, WswzB, WswzH, WswzO,
                                        bihb, bhhb, bf1, bf2_, d_out, flag);
}

// Round 14
// 990.632 us; speedup vs baseline: 1.4205x; 1.0060x over previous
//
#include <hip/hip_runtime.h>
#include <hip/hip_bf16.h>
#include <cstdint>
#include <cstddef>

#define N_NODES 20000
#define N_EDGES 640000
#define HID     128
#define OUT_DIM 64
#define NSTEPS  16
#define HSTEP   0.1f

typedef unsigned short u16;
typedef __attribute__((ext_vector_type(8))) short short8;   // 8 bf16 (4 VGPRs)
typedef __attribute__((ext_vector_type(4))) float f32x4;    // MFMA C/D

__device__ __forceinline__ float bf2f(u16 u) {
    union { unsigned int i; float f; } v; v.i = ((unsigned int)u) << 16; return v.f;
}
__device__ __forceinline__ u16 f2bf(float f) {
    union { float f; unsigned int i; } v; v.f = f;
    unsigned int x = v.i;
    unsigned int r = x + 0x7FFFu + ((x >> 16) & 1u);   // round-to-nearest-even
    return (u16)(r >> 16);
}

__device__ __forceinline__ float sigm(float x) { return 1.f / (1.f + __expf(-x)); }
__device__ __forceinline__ float tanh_fast(float x) {
    float e2 = __expf(-2.f * fabsf(x));
    float t = (1.f - e2) / (1.f + e2);
    return copysignf(t, x);
}

// ---------------------------------------------------------------------------
// Storage-dtype detection. flag=1 -> tensors stored as f32; flag=0 -> bf16.
// ---------------------------------------------------------------------------
__global__ void detect_kernel(const u16* __restrict__ xraw, int* __restrict__ flag) {
    __shared__ int cnt;
    if (threadIdx.x == 0) cnt = 0;
    __syncthreads();
    int c = 0;
    for (int i = threadIdx.x; i < 4096; i += 256) {
        int e = (xraw[i] >> 7) & 0xFF;
        if (e >= 0x90) c++;
    }
    atomicAdd(&cnt, c);
    __syncthreads();
    if (threadIdx.x == 0) *flag = (cnt > 100) ? 1 : 0;
}

// ---------------------------------------------------------------------------
// Packed conversion of the 15 weight/bias tensors into contiguous f32 ws.
// ---------------------------------------------------------------------------
#define N_CVT 15
struct CvtArgs { const void* s[N_CVT]; };
__constant__ const int cvt_off[N_CVT + 1] = {
    0, 16384, 16512, 32896, 33024, 98560, 164096, 164608, 165120,
    230656, 231168, 231680, 264448, 264576, 272768, 272832 };

__global__ void convert_kernel(CvtArgs a, float* __restrict__ dst,
                               const int* __restrict__ flag) {
    int i = blockIdx.x * blockDim.x + threadIdx.x;
    if (i >= 272832) return;
    int seg = 0;
    #pragma unroll
    for (int s = 1; s < N_CVT; ++s) if (i >= cvt_off[s]) seg = s;
    int j = i - cvt_off[seg];
    float v = (*flag) ? ((const float*)a.s[seg])[j]
                      : bf2f(((const u16*)a.s[seg])[j]);
    dst[i] = v;
}

// ---------------------------------------------------------------------------
// Build bf16 weights in MFMA B-fragment-swizzled order.
// elem (nt, ck, lane, j) = W[nt*16 + (lane&15)][ck*32 + (lane>>4)*8 + j]
// flat o = ((nt*NCK + ck)*64 + lane)*8 + j.
// ---------------------------------------------------------------------------
__global__ void build_wswz_kernel(const float* __restrict__ wsf,
                                  u16* __restrict__ WswzF, u16* __restrict__ WswzB,
                                  u16* __restrict__ WswzH, u16* __restrict__ WswzO,
                                  u16* __restrict__ WswzE1, u16* __restrict__ WswzE2) {
    int o = blockIdx.x * blockDim.x + threadIdx.x;
    if (o < 131072) {   // forward [Wihf|Whhf], NCK=8
        int j = o & 7, l = (o >> 3) & 63, rest = o >> 9;
        int ck = rest & 7, nt = rest >> 3;
        int n = nt * 16 + (l & 15);
        int k = ck * 32 + (l >> 4) * 8 + j;
        const float* Wihf = wsf + 33024;
        const float* Whhf = wsf + 98560;
        float v = (k < 128) ? Wihf[n * 128 + k] : Whhf[n * 128 + (k - 128)];
        WswzF[o] = f2bf(v);
    }
    if (o < 65536) {    // backward Wihb, NCK=4
        int j = o & 7, l = (o >> 3) & 63, rest = o >> 9;
        int ck = rest & 3, nt = rest >> 2;
        int n = nt * 16 + (l & 15);
        int k = ck * 32 + (l >> 4) * 8 + j;
        const float* Wihb = wsf + 165120;
        WswzB[o] = f2bf(Wihb[n * 128 + k]);
    }
    if (o < 32768) {    // fc1 Wf1 [128][256], NCK=8
        int j = o & 7, l = (o >> 3) & 63, rest = o >> 9;
        int ck = rest & 7, nt = rest >> 3;
        int n = nt * 16 + (l & 15);
        int k = ck * 32 + (l >> 4) * 8 + j;
        const float* Wf1 = wsf + 231680;
        WswzH[o] = f2bf(Wf1[n * 256 + k]);
    }
    if (o < 8192) {     // fc2 Wf2 [64][128], NCK=4
        int j = o & 7, l = (o >> 3) & 63, rest = o >> 9;
        int ck = rest & 3, nt = rest >> 2;
        int n = nt * 16 + (l & 15);
        int k = ck * 32 + (l >> 4) * 8 + j;
        const float* Wf2 = wsf + 264576;
        WswzO[o] = f2bf(Wf2[n * 128 + k]);
    }
    if (o < 16384) {    // enc1 Wenc1 [128][128], NCK=4, and enc2 Wenc2
        int j = o & 7, l = (o >> 3) & 63, rest = o >> 9;
        int ck = rest & 3, nt = rest >> 2;
        int n = nt * 16 + (l & 15);
        int k = ck * 32 + (l >> 4) * 8 + j;
        const float* We1 = wsf + 0;
        const float* We2 = wsf + 16512;
        WswzE1[o] = f2bf(We1[n * 128 + k]);
        WswzE2[o] = f2bf(We2[n * 128 + k]);
    }
}

// ---------------------------------------------------------------------------
// CSR build: degree count -> exclusive scan -> bucket fill
// ---------------------------------------------------------------------------
__global__ void count_kernel(const int* __restrict__ ei, int* __restrict__ deg) {
    int e = blockIdx.x * blockDim.x + threadIdx.x;
    if (e < N_EDGES) atomicAdd(&deg[ei[N_EDGES + e]], 1);
}

__global__ __launch_bounds__(1024) void scan_kernel(const int* __restrict__ deg,
                                                    int* __restrict__ rowptr,
                                                    float* __restrict__ degf) {
    __shared__ int sd[1024];
    const int t = threadIdx.x;
    const int CH = (N_NODES + 1023) / 1024;   // 20
    int base = t * CH;
    int s = 0;
    for (int i = 0; i < CH; ++i) {
        int idx = base + i;
        if (idx < N_NODES) s += deg[idx];
    }
    sd[t] = s;
    __syncthreads();
    for (int off = 1; off < 1024; off <<= 1) {
        int v = (t >= off) ? sd[t - off] : 0;
        __syncthreads();
        sd[t] += v;
        __syncthreads();
    }
    int run = (t == 0) ? 0 : sd[t - 1];
    for (int i = 0; i < CH; ++i) {
        int idx = base + i;
        if (idx < N_NODES) {
            rowptr[idx] = run;
            degf[idx] = (float)deg[idx];
            run += deg[idx];
        }
    }
    if (t == 1023) rowptr[N_NODES] = sd[1023];
}

__global__ void fill_kernel(const int* __restrict__ ei, const int* __restrict__ rowptr,
                            int* __restrict__ fill, int* __restrict__ csr) {
    int e = blockIdx.x * blockDim.x + threadIdx.x;
    if (e < N_EDGES) {
        int d = ei[N_EDGES + e];
        int p = atomicAdd(&fill[d], 1);
        csr[rowptr[d] + p] = ei[e];
    }
}

// ---------------------------------------------------------------------------
// Fused encoder (one dispatch): enc1 -> H1 (LDS bf16) -> enc2 -> Xa + XbfA.
// ---------------------------------------------------------------------------
__global__ __launch_bounds__(512) void encoder_kernel(
    const void* __restrict__ xv,
    const u16* __restrict__ WswzE1, const u16* __restrict__ WswzE2,
    const float* __restrict__ benc1, const float* __restrict__ benc2,
    float* __restrict__ Xa, u16* __restrict__ XbfA, const int* __restrict__ flag)
{
    __shared__ __align__(16) u16 H1[32][136];
    const int w = threadIdx.x >> 6;
    const int l = threadIdx.x & 63;
    const int l15 = l & 15, quad = l >> 4;
    const int m0 = blockIdx.x * 32;
    const int kof = quad * 8;
    const int j = w * 16 + l15;
    const bool xf32 = (*flag != 0);

    f32x4 acc[2] = {};
    #pragma unroll
    for (int ck = 0; ck < 4; ++ck) {
        const int kc = ck * 32;
        short8 a0, a1;
        if (xf32) {
            const float* r0 = (const float*)xv + (size_t)(m0 + l15) * HID + kc + kof;
            const float* r1 = (const float*)xv + (size_t)(m0 + 16 + l15) * HID + kc + kof;
            union { u16 u[8]; short8 v; } t0, t1;
            #pragma unroll
            for (int e = 0; e < 8; ++e) { t0.u[e] = f2bf(r0[e]); t1.u[e] = f2bf(r1[e]); }
            a0 = t0.v; a1 = t1.v;
        } else {
            a0 = *(const short8*)((const u16*)xv + (size_t)(m0 + l15) * HID + kc + kof);
            a1 = *(const short8*)((const u16*)xv + (size_t)(m0 + 16 + l15) * HID + kc + kof);
        }
        short8 b = *(const short8*)(WswzE1 + (((size_t)(w * 4 + ck)) << 9) + (l << 3));
        acc[0] = __builtin_amdgcn_mfma_f32_16x16x32_bf16(a0, b, acc[0], 0, 0, 0);
        acc[1] = __builtin_amdgcn_mfma_f32_16x16x32_bf16(a1, b, acc[1], 0, 0, 0);
    }
    {
        const float bj = benc1[j];
        #pragma unroll
        for (int mt = 0; mt < 2; ++mt)
            #pragma unroll
            for (int i = 0; i < 4; ++i)
                H1[mt * 16 + quad * 4 + i][j] = f2bf(fmaxf(acc[mt][i] + bj, 0.f));
    }
    __syncthreads();

    f32x4 acc2[2] = {};
    #pragma unroll
    for (int ck = 0; ck < 4; ++ck) {
        const int kc = ck * 32;
        short8 a0 = *(const short8*)(&H1[l15][kc + kof]);
        short8 a1 = *(const short8*)(&H1[16 + l15][kc + kof]);
        short8 b = *(const short8*)(WswzE2 + (((size_t)(w * 4 + ck)) << 9) + (l << 3));
        acc2[0] = __builtin_amdgcn_mfma_f32_16x16x32_bf16(a0, b, acc2[0], 0, 0, 0);
        acc2[1] = __builtin_amdgcn_mfma_f32_16x16x32_bf16(a1, b, acc2[1], 0, 0, 0);
    }
    {
        const float bj = benc2[j];
        #pragma unroll
        for (int mt = 0; mt < 2; ++mt)
            #pragma unroll
            for (int i = 0; i < 4; ++i) {
                int m = m0 + mt * 16 + quad * 4 + i;
                float o = acc2[mt][i] + bj;
                Xa[(size_t)m * HID + j] = o;
                XbfA[(size_t)m * HID + j] = f2bf(o);
            }
    }
}

// ---------------------------------------------------------------------------
// t=0 LSTM: zero h and c -> gates depend only on X (K=128, x-half of WswzF,
// B index nt*8+ck with ck<4); c = i*g; h = o*tanh(c). Writes cf + hbf (no
// memset needed — identical values to MFMA-against-zeros).
// ---------------------------------------------------------------------------
__global__ __launch_bounds__(512) void lstm0_kernel(
    const u16* __restrict__ Xbf, u16* __restrict__ hbf, float* __restrict__ cf,
    const u16* __restrict__ Wswz,
    const float* __restrict__ bih, const float* __restrict__ bhh)
{
    const int w = threadIdx.x >> 6;
    const int l = threadIdx.x & 63;
    const int l15 = l & 15, quad = l >> 4;
    const int m0 = blockIdx.x * 32;
    const int kof = quad * 8;

    f32x4 acc[2][4] = {};
    const size_t rowA0 = (size_t)(m0 + l15) * HID + kof;
    const size_t rowA1 = (size_t)(m0 + 16 + l15) * HID + kof;

    #pragma unroll
    for (int kc = 0; kc < 128; kc += 32) {
        const int ck = kc >> 5;
        short8 a0 = *(const short8*)(Xbf + rowA0 + kc);
        short8 a1 = *(const short8*)(Xbf + rowA1 + kc);
        #pragma unroll
        for (int q = 0; q < 4; ++q) {
            int nt = q * 8 + w;
            short8 b = *(const short8*)(Wswz + (((size_t)(nt * 8 + ck)) << 9) + (l << 3));
            acc[0][q] = __builtin_amdgcn_mfma_f32_16x16x32_bf16(a0, b, acc[0][q], 0, 0, 0);
            acc[1][q] = __builtin_amdgcn_mfma_f32_16x16x32_bf16(a1, b, acc[1][q], 0, 0, 0);
        }
    }

    const int j = w * 16 + l15;
    const float bI = bih[j]       + bhh[j];
    const float bG = bih[256 + j] + bhh[256 + j];
    const float bO = bih[384 + j] + bhh[384 + j];
    #pragma unroll
    for (int mt = 0; mt < 2; ++mt) {
        #pragma unroll
        for (int i = 0; i < 4; ++i) {
            int m = m0 + mt * 16 + quad * 4 + i;
            size_t off = (size_t)m * HID + j;
            float gi = sigm(acc[mt][0][i] + bI);
            float gg = tanh_fast(acc[mt][2][i] + bG);
            float go = sigm(acc[mt][3][i] + bO);
            float cn = gi * gg;
            cf[off] = cn;
            hbf[off] = f2bf(go * tanh_fast(cn));
        }
    }
}

// ---------------------------------------------------------------------------
// Forward MFMA LSTM step (proven body). 512 threads / 8 waves, 32 rows.
// ---------------------------------------------------------------------------
__global__ __launch_bounds__(512) void lstm_fwd_kernel(
    const u16* __restrict__ Xbf, u16* hbf, float* cf,
    const u16* __restrict__ Wswz,
    const float* __restrict__ bih, const float* __restrict__ bhh)
{
    const int w = threadIdx.x >> 6;
    const int l = threadIdx.x & 63;
    const int l15 = l & 15, quad = l >> 4;
    const int m0 = blockIdx.x * 32;
    const int kof = quad * 8;

    f32x4 acc[2][4] = {};
    const size_t rowA0 = (size_t)(m0 + l15) * HID + kof;
    const size_t rowA1 = (size_t)(m0 + 16 + l15) * HID + kof;

    #pragma unroll
    for (int kc = 0; kc < 256; kc += 32) {
        const int ck = kc >> 5;
        const u16* Ab = (kc >= 128) ? hbf : Xbf;
        int kl = (kc >= 128) ? (kc - 128) : kc;
        short8 a0 = *(const short8*)(Ab + rowA0 + kl);
        short8 a1 = *(const short8*)(Ab + rowA1 + kl);
        #pragma unroll
        for (int q = 0; q < 4; ++q) {
            int nt = q * 8 + w;
            short8 b = *(const short8*)(Wswz + (((size_t)(nt * 8 + ck)) << 9) + (l << 3));
            acc[0][q] = __builtin_amdgcn_mfma_f32_16x16x32_bf16(a0, b, acc[0][q], 0, 0, 0);
            acc[1][q] = __builtin_amdgcn_mfma_f32_16x16x32_bf16(a1, b, acc[1][q], 0, 0, 0);
        }
    }

    const int j = w * 16 + l15;
    const float bI = bih[j]       + bhh[j];
    const float bF = bih[128 + j] + bhh[128 + j];
    const float bG = bih[256 + j] + bhh[256 + j];
    const float bO = bih[384 + j] + bhh[384 + j];
    #pragma unroll
    for (int mt = 0; mt < 2; ++mt) {
        #pragma unroll
        for (int i = 0; i < 4; ++i) {
            int m = m0 + mt * 16 + quad * 4 + i;
            size_t off = (size_t)m * HID + j;
            float gi = sigm(acc[mt][0][i] + bI);
            float gf = sigm(acc[mt][1][i] + bF);
            float gg = tanh_fast(acc[mt][2][i] + bG);
            float go = sigm(acc[mt][3][i] + bO);
            float cn = gf * cf[off] + gi * gg;
            cf[off] = cn;
            hbf[off] = f2bf(go * tanh_fast(cn));
        }
    }
}

// ---------------------------------------------------------------------------
// Wave step v6: one node per wave; QUARTER-WAVE edges — quarter q = lane>>4
// takes edge-slot q, each lane short8 (8 feats, 16B) -> 4 edges per gather
// instruction; 4-group unroll -> 16 edges in flight (2x v5 MLP). Two-stage
// __shfl_xor merge (16, 32). FIRST: Y treated as 0 (not read) -> no memset.
// f32 X/Y updated in place (own row only); bf16 snapshot to XbfN.
// ---------------------------------------------------------------------------
template<bool FIRST>
__global__ __launch_bounds__(256) void wave_kernel(
    float* __restrict__ Xf, const u16* __restrict__ XbfP, u16* __restrict__ XbfN,
    float* __restrict__ Y, const float* __restrict__ degf,
    const int* __restrict__ rowptr, const int* __restrict__ csr)
{
    const int node = blockIdx.x * 4 + (threadIdx.x >> 6);
    const int lane = threadIdx.x & 63;
    const int q = lane >> 4;             // edge quarter 0..3
    const int fl = (lane & 15) * 8;      // 8 features per lane

    const int beg = rowptr[node], end = rowptr[node + 1];
    float s0[8] = {}, s1[8] = {}, s2[8] = {}, s3[8] = {};

    int i = beg;
    for (; i + 16 <= end; i += 16) {
        int v0 = csr[i + 0 + q];
        int v1 = csr[i + 4 + q];
        int v2 = csr[i + 8 + q];
        int v3 = csr[i + 12 + q];
        short8 g0 = *(const short8*)(XbfP + (size_t)v0 * HID + fl);
        short8 g1 = *(const short8*)(XbfP + (size_t)v1 * HID + fl);
        short8 g2 = *(const short8*)(XbfP + (size_t)v2 * HID + fl);
        short8 g3 = *(const short8*)(XbfP + (size_t)v3 * HID + fl);
        #pragma unroll
        for (int e = 0; e < 8; ++e) {
            s0[e] += bf2f((u16)g0[e]);
            s1[e] += bf2f((u16)g1[e]);
            s2[e] += bf2f((u16)g2[e]);
            s3[e] += bf2f((u16)g3[e]);
        }
    }
    for (; i + 4 <= end; i += 4) {       // 4-edge tail chunks
        int v = csr[i + q];
        short8 g = *(const short8*)(XbfP + (size_t)v * HID + fl);
        #pragma unroll
        for (int e = 0; e < 8; ++e) s0[e] += bf2f((u16)g[e]);
    }
    if (i + q < end) {                   // final <4 edges: quarter q takes i+q
        int v = csr[i + q];
        short8 g = *(const short8*)(XbfP + (size_t)v * HID + fl);
        #pragma unroll
        for (int e = 0; e < 8; ++e) s1[e] += bf2f((u16)g[e]);
    }

    float t[8];
    #pragma unroll
    for (int e = 0; e < 8; ++e) {
        t[e] = (s0[e] + s1[e]) + (s2[e] + s3[e]);
        t[e] += __shfl_xor(t[e], 16, 64);
        t[e] += __shfl_xor(t[e], 32, 64);
    }

    if (q == 0) {
        const size_t off = (size_t)node * HID + fl;
        float xv[8], yv[8], xn[8];
        *(float4*)&xv[0] = *(const float4*)(Xf + off);
        *(float4*)&xv[4] = *(const float4*)(Xf + off + 4);
        if (!FIRST) {
            *(float4*)&yv[0] = *(const float4*)(Y + off);
            *(float4*)&yv[4] = *(const float4*)(Y + off + 4);
        }
        const float d = degf[node];
        short8 sv;
        #pragma unroll
        for (int e = 0; e < 8; ++e) {
            float y = (FIRST ? 0.f : yv[e]) - HSTEP * (d * xv[e] - t[e]);
            yv[e] = y;
            xn[e] = xv[e] + HSTEP * y;
            sv[e] = (short)f2bf(xn[e]);
        }
        *(float4*)(Y + off)      = *(float4*)&yv[0];
        *(float4*)(Y + off + 4)  = *(float4*)&yv[4];
        *(float4*)(Xf + off)     = *(float4*)&xn[0];
        *(float4*)(Xf + off + 4) = *(float4*)&xn[4];
        *(short8*)(XbfN + off)   = sv;
    }
}

// ---------------------------------------------------------------------------
// Fused tail (one dispatch): bwd cell -> Hb (LDS) -> fc1 -> F1 (LDS) -> fc2.
// ---------------------------------------------------------------------------
__global__ __launch_bounds__(512) void tail_kernel(
    const u16* __restrict__ Xbf, const u16* __restrict__ hbf,
    const u16* __restrict__ WswzB, const u16* __restrict__ WswzH,
    const u16* __restrict__ WswzO,
    const float* __restrict__ bihb, const float* __restrict__ bhhb,
    const float* __restrict__ bf1, const float* __restrict__ bf2_,
    void* __restrict__ out, const int* __restrict__ oflag)
{
    __shared__ __align__(16) u16 Hb[32][136];
    __shared__ __align__(16) u16 F1[32][136];
    const int w = threadIdx.x >> 6;
    const int l = threadIdx.x & 63;
    const int l15 = l & 15, quad = l >> 4;
    const int m0 = blockIdx.x * 32;
    const int kof = quad * 8;
    const int j = w * 16 + l15;

    // ---- phase 1: backward cell -> Hb ----
    {
        f32x4 acc[2][4] = {};
        const size_t rowA0 = (size_t)(m0 + l15) * HID + kof;
        const size_t rowA1 = (size_t)(m0 + 16 + l15) * HID + kof;
        #pragma unroll
        for (int kc = 0; kc < 128; kc += 32) {
            const int ck = kc >> 5;
            short8 a0 = *(const short8*)(Xbf + rowA0 + kc);
            short8 a1 = *(const short8*)(Xbf + rowA1 + kc);
            #pragma unroll
            for (int q = 0; q < 4; ++q) {
                int nt = q * 8 + w;
                short8 b = *(const short8*)(WswzB + (((size_t)(nt * 4 + ck)) << 9) + (l << 3));
                acc[0][q] = __builtin_amdgcn_mfma_f32_16x16x32_bf16(a0, b, acc[0][q], 0, 0, 0);
                acc[1][q] = __builtin_amdgcn_mfma_f32_16x16x32_bf16(a1, b, acc[1][q], 0, 0, 0);
            }
        }
        const float bI = bihb[j]       + bhhb[j];
        const float bG = bihb[256 + j] + bhhb[256 + j];
        const float bO = bihb[384 + j] + bhhb[384 + j];
        #pragma unroll
        for (int mt = 0; mt < 2; ++mt)
            #pragma unroll
            for (int i = 0; i < 4; ++i) {
                float gi = sigm(acc[mt][0][i] + bI);
                float gg = tanh_fast(acc[mt][2][i] + bG);
                float go = sigm(acc[mt][3][i] + bO);
                Hb[mt * 16 + quad * 4 + i][j] = f2bf(go * tanh_fast(gi * gg));
            }
    }
    __syncthreads();

    // ---- phase 2: fc1 -> F1 ----
    {
        f32x4 acc[2] = {};
        #pragma unroll
        for (int kc = 0; kc < 256; kc += 32) {
            const int ck = kc >> 5;
            short8 a0, a1;
            if (kc < 128) {
                a0 = *(const short8*)(hbf + (size_t)(m0 + l15) * HID + kc + kof);
                a1 = *(const short8*)(hbf + (size_t)(m0 + 16 + l15) * HID + kc + kof);
            } else {
                a0 = *(const short8*)(&Hb[l15][(kc - 128) + kof]);
                a1 = *(const short8*)(&Hb[16 + l15][(kc - 128) + kof]);
            }
            short8 b = *(const short8*)(WswzH + (((size_t)(w * 8 + ck)) << 9) + (l << 3));
            acc[0] = __builtin_amdgcn_mfma_f32_16x16x32_bf16(a0, b, acc[0], 0, 0, 0);
            acc[1] = __builtin_amdgcn_mfma_f32_16x16x32_bf16(a1, b, acc[1], 0, 0, 0);
        }
        const float bj = bf1[j];
        #pragma unroll
        for (int mt = 0; mt < 2; ++mt)
            #pragma unroll
            for (int i = 0; i < 4; ++i)
                F1[mt * 16 + quad * 4 + i][j] = f2bf(fmaxf(acc[mt][i] + bj, 0.f));
    }
    __syncthreads();

    // ---- phase 3: fc2 -> out ----
    {
        const int nt = w & 3, mh = w >> 2;
        f32x4 acc = {};
        #pragma unroll
        for (int kc = 0; kc < 128; kc += 32) {
            const int ck = kc >> 5;
            short8 a = *(const short8*)(&F1[mh * 16 + l15][kc + kof]);
            short8 b = *(const short8*)(WswzO + (((size_t)(nt * 4 + ck)) << 9) + (l << 3));
            acc = __builtin_amdgcn_mfma_f32_16x16x32_bf16(a, b, acc, 0, 0, 0);
        }
        const int jo = nt * 16 + l15;
        const float bj = bf2_[jo];
        const bool obf = (*oflag == 0);
        #pragma unroll
        for (int i = 0; i < 4; ++i) {
            int m = m0 + mh * 16 + quad * 4 + i;
            float o = acc[i] + bj;
            if (obf) ((u16*)out)[(size_t)m * OUT_DIM + jo] = f2bf(o);
            else     ((float*)out)[(size_t)m * OUT_DIM + jo] = o;
        }
    }
}

// ---------------------------------------------------------------------------
extern "C" void kernel_launch(void* const* d_in, const int* in_sizes, int n_in,
                              void* d_out, int out_size, void* d_ws, size_t ws_size,
                              hipStream_t stream)
{
    const void* x  = d_in[0];
    const int*  ei = (const int*)d_in[1];

    const size_t SZ_NH  = (size_t)N_NODES * HID * sizeof(float);   // 10,240,000
    const size_t SZ_NHB = (size_t)N_NODES * HID * sizeof(u16);     //  5,120,000
    const size_t SZ_I   = 80128;

    char* p = (char*)d_ws;
    float* Xa    = (float*)p; p += SZ_NH;
    float* Y     = (float*)p; p += SZ_NH;
    float* cf    = (float*)p; p += SZ_NH;
    u16*   hbf   = (u16*)p;   p += SZ_NHB;
    u16*   XbfA  = (u16*)p;   p += SZ_NHB;
    u16*   XbfB  = (u16*)p;   p += SZ_NHB;
    int*   deg   = (int*)p;   p += SZ_I;
    int*   fill  = (int*)p;   p += SZ_I;
    int*   rowp  = (int*)p;   p += SZ_I;
    float* degf  = (float*)p; p += SZ_I;
    int*   csr   = (int*)p;   p += (size_t)N_EDGES * sizeof(int);
    int*   flag  = (int*)p;   p += 128;
    float* wsf   = (float*)p; p += 272832 * sizeof(float);
    u16*   WswzF  = (u16*)p;  p += 131072 * sizeof(u16);
    u16*   WswzB  = (u16*)p;  p += 65536 * sizeof(u16);
    u16*   WswzH  = (u16*)p;  p += 32768 * sizeof(u16);
    u16*   WswzO  = (u16*)p;  p += 8192 * sizeof(u16);
    u16*   WswzE1 = (u16*)p;  p += 16384 * sizeof(u16);
    u16*   WswzE2 = (u16*)p;  p += 16384 * sizeof(u16);

    // converted f32 weight sub-pointers (offsets match cvt_off)
    float* benc1 = wsf + 16384;
    float* benc2 = wsf + 32896;
    float* bihf  = wsf + 164096;
    float* bhhf  = wsf + 164608;
    float* bihb  = wsf + 230656;
    float* bhhb  = wsf + 231168;
    float* bf1   = wsf + 264448;
    float* bf2_  = wsf + 272768;

    // NOTE: no Y/cf/hbf memset — lstm0 writes cf/hbf, wave<FIRST> writes Y
    hipMemsetAsync(deg, 0, 2 * SZ_I, stream);           // deg, fill (contiguous)

    // dtype detect + weight conversion (f32 master, swizzled bf16 MFMA copies)
    detect_kernel<<<1, 256, 0, stream>>>((const u16*)x, flag);
    CvtArgs ca;
    ca.s[0] = d_in[2];  ca.s[1] = d_in[3];  ca.s[2] = d_in[4];  ca.s[3] = d_in[5];
    ca.s[4] = d_in[6];  ca.s[5] = d_in[7];  ca.s[6] = d_in[8];  ca.s[7] = d_in[9];
    ca.s[8] = d_in[10]; ca.s[9] = d_in[12]; ca.s[10] = d_in[13];
    ca.s[11] = d_in[14]; ca.s[12] = d_in[15]; ca.s[13] = d_in[16]; ca.s[14] = d_in[17];
    convert_kernel<<<(272832 + 255) / 256, 256, 0, stream>>>(ca, wsf, flag);
    build_wswz_kernel<<<512, 256, 0, stream>>>(wsf, WswzF, WswzB, WswzH, WswzO,
                                               WswzE1, WswzE2);

    // CSR build
    count_kernel<<<(N_EDGES + 255) / 256, 256, 0, stream>>>(ei, deg);
    scan_kernel<<<1, 1024, 0, stream>>>(deg, rowp, degf);
    fill_kernel<<<(N_EDGES + 255) / 256, 256, 0, stream>>>(ei, rowp, fill, csr);

    const int NB = N_NODES / 32;          // 625

    // fused encoder: x -> X0 (Xa f32 + XbfA bf16), one dispatch
    encoder_kernel<<<NB, 512, 0, stream>>>(x, WswzE1, WswzE2, benc1, benc2,
                                           Xa, XbfA, flag);

    // t=0 zero-state LSTM (writes cf/hbf), then 15 x (wave -> LSTM)
    lstm0_kernel<<<NB, 512, 0, stream>>>(XbfA, hbf, cf, WswzF, bihf, bhhf);
    u16* XbP = XbfA;
    u16* XbN = XbfB;
    for (int t = 1; t < NSTEPS; ++t) {
        if (t == 1)
            wave_kernel<true><<<N_NODES / 4, 256, 0, stream>>>(
                Xa, XbP, XbN, Y, degf, rowp, csr);
        else
            wave_kernel<false><<<N_NODES / 4, 256, 0, stream>>>(
                Xa, XbP, XbN, Y, degf, rowp, csr);
        u16* tmp = XbP; XbP = XbN; XbN = tmp;
        lstm_fwd_kernel<<<NB, 512, 0, stream>>>(XbP, hbf, cf, WswzF, bihf, bhhf);
    }

    // fused tail: backward cell + fc1 + fc2, one dispatch
    tail_kernel<<<NB, 512, 0, stream>>>(XbP, hbf, WswzB, WswzH, WswzO,
                                        bihb, bhhb, bf1, bf2_, d_out, flag);
}

// Round 15
// 971.937 us; speedup vs baseline: 1.4479x; 1.0192x over previous
//
#include <hip/hip_runtime.h>
#include <hip/hip_bf16.h>
#include <cstdint>
#include <cstddef>

#define N_NODES 20000
#define N_EDGES 640000
#define HID     128
#define OUT_DIM 64
#define NSTEPS  16
#define HSTEP   0.1f
#define H2      0.01f          // HSTEP^2 (leapfrog coefficient)

typedef unsigned short u16;
typedef __attribute__((ext_vector_type(8))) short short8;   // 8 bf16 (4 VGPRs)
typedef __attribute__((ext_vector_type(4))) float f32x4;    // MFMA C/D

__device__ __forceinline__ float bf2f(u16 u) {
    union { unsigned int i; float f; } v; v.i = ((unsigned int)u) << 16; return v.f;
}
__device__ __forceinline__ u16 f2bf(float f) {
    union { float f; unsigned int i; } v; v.f = f;
    unsigned int x = v.i;
    unsigned int r = x + 0x7FFFu + ((x >> 16) & 1u);   // round-to-nearest-even
    return (u16)(r >> 16);
}

__device__ __forceinline__ float sigm(float x) { return 1.f / (1.f + __expf(-x)); }
__device__ __forceinline__ float tanh_fast(float x) {
    float e2 = __expf(-2.f * fabsf(x));
    float t = (1.f - e2) / (1.f + e2);
    return copysignf(t, x);
}

// ---------------------------------------------------------------------------
// Storage-dtype detection. flag=1 -> tensors stored as f32; flag=0 -> bf16.
// ---------------------------------------------------------------------------
__global__ void detect_kernel(const u16* __restrict__ xraw, int* __restrict__ flag) {
    __shared__ int cnt;
    if (threadIdx.x == 0) cnt = 0;
    __syncthreads();
    int c = 0;
    for (int i = threadIdx.x; i < 4096; i += 256) {
        int e = (xraw[i] >> 7) & 0xFF;
        if (e >= 0x90) c++;
    }
    atomicAdd(&cnt, c);
    __syncthreads();
    if (threadIdx.x == 0) *flag = (cnt > 100) ? 1 : 0;
}

// ---------------------------------------------------------------------------
// Packed conversion of the 15 weight/bias tensors into contiguous f32 ws.
// ---------------------------------------------------------------------------
#define N_CVT 15
struct CvtArgs { const void* s[N_CVT]; };
__constant__ const int cvt_off[N_CVT + 1] = {
    0, 16384, 16512, 32896, 33024, 98560, 164096, 164608, 165120,
    230656, 231168, 231680, 264448, 264576, 272768, 272832 };

__global__ void convert_kernel(CvtArgs a, float* __restrict__ dst,
                               const int* __restrict__ flag) {
    int i = blockIdx.x * blockDim.x + threadIdx.x;
    if (i >= 272832) return;
    int seg = 0;
    #pragma unroll
    for (int s = 1; s < N_CVT; ++s) if (i >= cvt_off[s]) seg = s;
    int j = i - cvt_off[seg];
    float v = (*flag) ? ((const float*)a.s[seg])[j]
                      : bf2f(((const u16*)a.s[seg])[j]);
    dst[i] = v;
}

// ---------------------------------------------------------------------------
// Build bf16 weights in MFMA B-fragment-swizzled order.
// elem (nt, ck, lane, j) = W[nt*16 + (lane&15)][ck*32 + (lane>>4)*8 + j]
// flat o = ((nt*NCK + ck)*64 + lane)*8 + j.
// ---------------------------------------------------------------------------
__global__ void build_wswz_kernel(const float* __restrict__ wsf,
                                  u16* __restrict__ WswzF, u16* __restrict__ WswzB,
                                  u16* __restrict__ WswzH, u16* __restrict__ WswzO,
                                  u16* __restrict__ WswzE1, u16* __restrict__ WswzE2) {
    int o = blockIdx.x * blockDim.x + threadIdx.x;
    if (o < 131072) {   // forward [Wihf|Whhf], NCK=8
        int j = o & 7, l = (o >> 3) & 63, rest = o >> 9;
        int ck = rest & 7, nt = rest >> 3;
        int n = nt * 16 + (l & 15);
        int k = ck * 32 + (l >> 4) * 8 + j;
        const float* Wihf = wsf + 33024;
        const float* Whhf = wsf + 98560;
        float v = (k < 128) ? Wihf[n * 128 + k] : Whhf[n * 128 + (k - 128)];
        WswzF[o] = f2bf(v);
    }
    if (o < 65536) {    // backward Wihb, NCK=4
        int j = o & 7, l = (o >> 3) & 63, rest = o >> 9;
        int ck = rest & 3, nt = rest >> 2;
        int n = nt * 16 + (l & 15);
        int k = ck * 32 + (l >> 4) * 8 + j;
        const float* Wihb = wsf + 165120;
        WswzB[o] = f2bf(Wihb[n * 128 + k]);
    }
    if (o < 32768) {    // fc1 Wf1 [128][256], NCK=8
        int j = o & 7, l = (o >> 3) & 63, rest = o >> 9;
        int ck = rest & 7, nt = rest >> 3;
        int n = nt * 16 + (l & 15);
        int k = ck * 32 + (l >> 4) * 8 + j;
        const float* Wf1 = wsf + 231680;
        WswzH[o] = f2bf(Wf1[n * 256 + k]);
    }
    if (o < 8192) {     // fc2 Wf2 [64][128], NCK=4
        int j = o & 7, l = (o >> 3) & 63, rest = o >> 9;
        int ck = rest & 3, nt = rest >> 2;
        int n = nt * 16 + (l & 15);
        int k = ck * 32 + (l >> 4) * 8 + j;
        const float* Wf2 = wsf + 264576;
        WswzO[o] = f2bf(Wf2[n * 128 + k]);
    }
    if (o < 16384) {    // enc1 Wenc1 [128][128], NCK=4, and enc2 Wenc2
        int j = o & 7, l = (o >> 3) & 63, rest = o >> 9;
        int ck = rest & 3, nt = rest >> 2;
        int n = nt * 16 + (l & 15);
        int k = ck * 32 + (l >> 4) * 8 + j;
        const float* We1 = wsf + 0;
        const float* We2 = wsf + 16512;
        WswzE1[o] = f2bf(We1[n * 128 + k]);
        WswzE2[o] = f2bf(We2[n * 128 + k]);
    }
}

// ---------------------------------------------------------------------------
// CSR build: degree count -> exclusive scan -> bucket fill
// ---------------------------------------------------------------------------
__global__ void count_kernel(const int* __restrict__ ei, int* __restrict__ deg) {
    int e = blockIdx.x * blockDim.x + threadIdx.x;
    if (e < N_EDGES) atomicAdd(&deg[ei[N_EDGES + e]], 1);
}

__global__ __launch_bounds__(1024) void scan_kernel(const int* __restrict__ deg,
                                                    int* __restrict__ rowptr,
                                                    float* __restrict__ degf) {
    __shared__ int sd[1024];
    const int t = threadIdx.x;
    const int CH = (N_NODES + 1023) / 1024;   // 20
    int base = t * CH;
    int s = 0;
    for (int i = 0; i < CH; ++i) {
        int idx = base + i;
        if (idx < N_NODES) s += deg[idx];
    }
    sd[t] = s;
    __syncthreads();
    for (int off = 1; off < 1024; off <<= 1) {
        int v = (t >= off) ? sd[t - off] : 0;
        __syncthreads();
        sd[t] += v;
        __syncthreads();
    }
    int run = (t == 0) ? 0 : sd[t - 1];
    for (int i = 0; i < CH; ++i) {
        int idx = base + i;
        if (idx < N_NODES) {
            rowptr[idx] = run;
            degf[idx] = (float)deg[idx];
            run += deg[idx];
        }
    }
    if (t == 1023) rowptr[N_NODES] = sd[1023];
}

__global__ void fill_kernel(const int* __restrict__ ei, const int* __restrict__ rowptr,
                            int* __restrict__ fill, int* __restrict__ csr) {
    int e = blockIdx.x * blockDim.x + threadIdx.x;
    if (e < N_EDGES) {
        int d = ei[N_EDGES + e];
        int p = atomicAdd(&fill[d], 1);
        csr[rowptr[d] + p] = ei[e];
    }
}

// ---------------------------------------------------------------------------
// Fused encoder (one dispatch): enc1 -> H1 (LDS bf16) -> enc2 -> Xa + XbfA.
// ---------------------------------------------------------------------------
__global__ __launch_bounds__(512) void encoder_kernel(
    const void* __restrict__ xv,
    const u16* __restrict__ WswzE1, const u16* __restrict__ WswzE2,
    const float* __restrict__ benc1, const float* __restrict__ benc2,
    float* __restrict__ Xa, u16* __restrict__ XbfA, const int* __restrict__ flag)
{
    __shared__ __align__(16) u16 H1[32][136];
    const int w = threadIdx.x >> 6;
    const int l = threadIdx.x & 63;
    const int l15 = l & 15, quad = l >> 4;
    const int m0 = blockIdx.x * 32;
    const int kof = quad * 8;
    const int j = w * 16 + l15;
    const bool xf32 = (*flag != 0);

    f32x4 acc[2] = {};
    #pragma unroll
    for (int ck = 0; ck < 4; ++ck) {
        const int kc = ck * 32;
        short8 a0, a1;
        if (xf32) {
            const float* r0 = (const float*)xv + (size_t)(m0 + l15) * HID + kc + kof;
            const float* r1 = (const float*)xv + (size_t)(m0 + 16 + l15) * HID + kc + kof;
            union { u16 u[8]; short8 v; } t0, t1;
            #pragma unroll
            for (int e = 0; e < 8; ++e) { t0.u[e] = f2bf(r0[e]); t1.u[e] = f2bf(r1[e]); }
            a0 = t0.v; a1 = t1.v;
        } else {
            a0 = *(const short8*)((const u16*)xv + (size_t)(m0 + l15) * HID + kc + kof);
            a1 = *(const short8*)((const u16*)xv + (size_t)(m0 + 16 + l15) * HID + kc + kof);
        }
        short8 b = *(const short8*)(WswzE1 + (((size_t)(w * 4 + ck)) << 9) + (l << 3));
        acc[0] = __builtin_amdgcn_mfma_f32_16x16x32_bf16(a0, b, acc[0], 0, 0, 0);
        acc[1] = __builtin_amdgcn_mfma_f32_16x16x32_bf16(a1, b, acc[1], 0, 0, 0);
    }
    {
        const float bj = benc1[j];
        #pragma unroll
        for (int mt = 0; mt < 2; ++mt)
            #pragma unroll
            for (int i = 0; i < 4; ++i)
                H1[mt * 16 + quad * 4 + i][j] = f2bf(fmaxf(acc[mt][i] + bj, 0.f));
    }
    __syncthreads();

    f32x4 acc2[2] = {};
    #pragma unroll
    for (int ck = 0; ck < 4; ++ck) {
        const int kc = ck * 32;
        short8 a0 = *(const short8*)(&H1[l15][kc + kof]);
        short8 a1 = *(const short8*)(&H1[16 + l15][kc + kof]);
        short8 b = *(const short8*)(WswzE2 + (((size_t)(w * 4 + ck)) << 9) + (l << 3));
        acc2[0] = __builtin_amdgcn_mfma_f32_16x16x32_bf16(a0, b, acc2[0], 0, 0, 0);
        acc2[1] = __builtin_amdgcn_mfma_f32_16x16x32_bf16(a1, b, acc2[1], 0, 0, 0);
    }
    {
        const float bj = benc2[j];
        #pragma unroll
        for (int mt = 0; mt < 2; ++mt)
            #pragma unroll
            for (int i = 0; i < 4; ++i) {
                int m = m0 + mt * 16 + quad * 4 + i;
                float o = acc2[mt][i] + bj;
                Xa[(size_t)m * HID + j] = o;
                XbfA[(size_t)m * HID + j] = f2bf(o);
            }
    }
}

// ---------------------------------------------------------------------------
// t=0 LSTM: zero h and c -> gates depend only on X (K=128, x-half of WswzF);
// c = i*g; h = o*tanh(c). Writes cf + hbf (no memset needed).
// ---------------------------------------------------------------------------
__global__ __launch_bounds__(512) void lstm0_kernel(
    const u16* __restrict__ Xbf, u16* __restrict__ hbf, float* __restrict__ cf,
    const u16* __restrict__ Wswz,
    const float* __restrict__ bih, const float* __restrict__ bhh)
{
    const int w = threadIdx.x >> 6;
    const int l = threadIdx.x & 63;
    const int l15 = l & 15, quad = l >> 4;
    const int m0 = blockIdx.x * 32;
    const int kof = quad * 8;

    f32x4 acc[2][4] = {};
    const size_t rowA0 = (size_t)(m0 + l15) * HID + kof;
    const size_t rowA1 = (size_t)(m0 + 16 + l15) * HID + kof;

    #pragma unroll
    for (int kc = 0; kc < 128; kc += 32) {
        const int ck = kc >> 5;
        short8 a0 = *(const short8*)(Xbf + rowA0 + kc);
        short8 a1 = *(const short8*)(Xbf + rowA1 + kc);
        #pragma unroll
        for (int q = 0; q < 4; ++q) {
            int nt = q * 8 + w;
            short8 b = *(const short8*)(Wswz + (((size_t)(nt * 8 + ck)) << 9) + (l << 3));
            acc[0][q] = __builtin_amdgcn_mfma_f32_16x16x32_bf16(a0, b, acc[0][q], 0, 0, 0);
            acc[1][q] = __builtin_amdgcn_mfma_f32_16x16x32_bf16(a1, b, acc[1][q], 0, 0, 0);
        }
    }

    const int j = w * 16 + l15;
    const float bI = bih[j]       + bhh[j];
    const float bG = bih[256 + j] + bhh[256 + j];
    const float bO = bih[384 + j] + bhh[384 + j];
    #pragma unroll
    for (int mt = 0; mt < 2; ++mt) {
        #pragma unroll
        for (int i = 0; i < 4; ++i) {
            int m = m0 + mt * 16 + quad * 4 + i;
            size_t off = (size_t)m * HID + j;
            float gi = sigm(acc[mt][0][i] + bI);
            float gg = tanh_fast(acc[mt][2][i] + bG);
            float go = sigm(acc[mt][3][i] + bO);
            float cn = gi * gg;
            cf[off] = cn;
            hbf[off] = f2bf(go * tanh_fast(cn));
        }
    }
}

// ---------------------------------------------------------------------------
// Forward MFMA LSTM step (proven body). 512 threads / 8 waves, 32 rows.
// ---------------------------------------------------------------------------
__global__ __launch_bounds__(512) void lstm_fwd_kernel(
    const u16* __restrict__ Xbf, u16* hbf, float* cf,
    const u16* __restrict__ Wswz,
    const float* __restrict__ bih, const float* __restrict__ bhh)
{
    const int w = threadIdx.x >> 6;
    const int l = threadIdx.x & 63;
    const int l15 = l & 15, quad = l >> 4;
    const int m0 = blockIdx.x * 32;
    const int kof = quad * 8;

    f32x4 acc[2][4] = {};
    const size_t rowA0 = (size_t)(m0 + l15) * HID + kof;
    const size_t rowA1 = (size_t)(m0 + 16 + l15) * HID + kof;

    #pragma unroll
    for (int kc = 0; kc < 256; kc += 32) {
        const int ck = kc >> 5;
        const u16* Ab = (kc >= 128) ? hbf : Xbf;
        int kl = (kc >= 128) ? (kc - 128) : kc;
        short8 a0 = *(const short8*)(Ab + rowA0 + kl);
        short8 a1 = *(const short8*)(Ab + rowA1 + kl);
        #pragma unroll
        for (int q = 0; q < 4; ++q) {
            int nt = q * 8 + w;
            short8 b = *(const short8*)(Wswz + (((size_t)(nt * 8 + ck)) << 9) + (l << 3));
            acc[0][q] = __builtin_amdgcn_mfma_f32_16x16x32_bf16(a0, b, acc[0][q], 0, 0, 0);
            acc[1][q] = __builtin_amdgcn_mfma_f32_16x16x32_bf16(a1, b, acc[1][q], 0, 0, 0);
        }
    }

    const int j = w * 16 + l15;
    const float bI = bih[j]       + bhh[j];
    const float bF = bih[128 + j] + bhh[128 + j];
    const float bG = bih[256 + j] + bhh[256 + j];
    const float bO = bih[384 + j] + bhh[384 + j];
    #pragma unroll
    for (int mt = 0; mt < 2; ++mt) {
        #pragma unroll
        for (int i = 0; i < 4; ++i) {
            int m = m0 + mt * 16 + quad * 4 + i;
            size_t off = (size_t)m * HID + j;
            float gi = sigm(acc[mt][0][i] + bI);
            float gf = sigm(acc[mt][1][i] + bF);
            float gg = tanh_fast(acc[mt][2][i] + bG);
            float go = sigm(acc[mt][3][i] + bO);
            float cn = gf * cf[off] + gi * gg;
            cf[off] = cn;
            hbf[off] = f2bf(go * tanh_fast(cn));
        }
    }
}

// ---------------------------------------------------------------------------
// Wave step v7 — LEAPFROG (Y eliminated):
//   X_t = (2 - H^2*deg)*X_{t-1} - X_{t-2} + H^2 * sum_nbr X_{t-1}
// (FIRST: X_{-1} := X_0, exactly reproducing the Y-form's first step.)
// Quarter-wave gather (4 edges/instr, 16 in flight) from bf16 snapshot;
// Xdst holds X_{t-2} and is overwritten with X_t (ping-pong); bf16
// snapshot to XbfN. Saves Y's 20 MB r/w per step (net -10 MB vs v6).
// ---------------------------------------------------------------------------
template<bool FIRST>
__global__ __launch_bounds__(256) void wave_kernel(
    const float* __restrict__ Xcur, float* __restrict__ Xdst,
    const u16* __restrict__ XbfP, u16* __restrict__ XbfN,
    const float* __restrict__ degf,
    const int* __restrict__ rowptr, const int* __restrict__ csr)
{
    const int node = blockIdx.x * 4 + (threadIdx.x >> 6);
    const int lane = threadIdx.x & 63;
    const int q = lane >> 4;             // edge quarter 0..3
    const int fl = (lane & 15) * 8;      // 8 features per lane

    const int beg = rowptr[node], end = rowptr[node + 1];
    float s0[8] = {}, s1[8] = {}, s2[8] = {}, s3[8] = {};

    int i = beg;
    for (; i + 16 <= end; i += 16) {
        int v0 = csr[i + 0 + q];
        int v1 = csr[i + 4 + q];
        int v2 = csr[i + 8 + q];
        int v3 = csr[i + 12 + q];
        short8 g0 = *(const short8*)(XbfP + (size_t)v0 * HID + fl);
        short8 g1 = *(const short8*)(XbfP + (size_t)v1 * HID + fl);
        short8 g2 = *(const short8*)(XbfP + (size_t)v2 * HID + fl);
        short8 g3 = *(const short8*)(XbfP + (size_t)v3 * HID + fl);
        #pragma unroll
        for (int e = 0; e < 8; ++e) {
            s0[e] += bf2f((u16)g0[e]);
            s1[e] += bf2f((u16)g1[e]);
            s2[e] += bf2f((u16)g2[e]);
            s3[e] += bf2f((u16)g3[e]);
        }
    }
    for (; i + 4 <= end; i += 4) {       // 4-edge tail chunks
        int v = csr[i + q];
        short8 g = *(const short8*)(XbfP + (size_t)v * HID + fl);
        #pragma unroll
        for (int e = 0; e < 8; ++e) s0[e] += bf2f((u16)g[e]);
    }
    if (i + q < end) {                   // final <4 edges: quarter q takes i+q
        int v = csr[i + q];
        short8 g = *(const short8*)(XbfP + (size_t)v * HID + fl);
        #pragma unroll
        for (int e = 0; e < 8; ++e) s1[e] += bf2f((u16)g[e]);
    }

    float t[8];
    #pragma unroll
    for (int e = 0; e < 8; ++e) {
        t[e] = (s0[e] + s1[e]) + (s2[e] + s3[e]);
        t[e] += __shfl_xor(t[e], 16, 64);
        t[e] += __shfl_xor(t[e], 32, 64);
    }

    if (q == 0) {
        const size_t off = (size_t)node * HID + fl;
        float xc[8], xp[8], xn[8];
        *(float4*)&xc[0] = *(const float4*)(Xcur + off);
        *(float4*)&xc[4] = *(const float4*)(Xcur + off + 4);
        if (!FIRST) {
            *(float4*)&xp[0] = *(const float4*)(Xdst + off);
            *(float4*)&xp[4] = *(const float4*)(Xdst + off + 4);
        }
        const float d = degf[node];
        const float c0 = 2.f - H2 * d;
        short8 sv;
        #pragma unroll
        for (int e = 0; e < 8; ++e) {
            float prev = FIRST ? xc[e] : xp[e];
            xn[e] = c0 * xc[e] - prev + H2 * t[e];
            sv[e] = (short)f2bf(xn[e]);
        }
        *(float4*)(Xdst + off)     = *(float4*)&xn[0];
        *(float4*)(Xdst + off + 4) = *(float4*)&xn[4];
        *(short8*)(XbfN + off)     = sv;
    }
}

// ---------------------------------------------------------------------------
// Fused tail (one dispatch): bwd cell -> Hb (LDS) -> fc1 -> F1 (LDS) -> fc2.
// ---------------------------------------------------------------------------
__global__ __launch_bounds__(512) void tail_kernel(
    const u16* __restrict__ Xbf, const u16* __restrict__ hbf,
    const u16* __restrict__ WswzB, const u16* __restrict__ WswzH,
    const u16* __restrict__ WswzO,
    const float* __restrict__ bihb, const float* __restrict__ bhhb,
    const float* __restrict__ bf1, const float* __restrict__ bf2_,
    void* __restrict__ out, const int* __restrict__ oflag)
{
    __shared__ __align__(16) u16 Hb[32][136];
    __shared__ __align__(16) u16 F1[32][136];
    const int w = threadIdx.x >> 6;
    const int l = threadIdx.x & 63;
    const int l15 = l & 15, quad = l >> 4;
    const int m0 = blockIdx.x * 32;
    const int kof = quad * 8;
    const int j = w * 16 + l15;

    // ---- phase 1: backward cell -> Hb ----
    {
        f32x4 acc[2][4] = {};
        const size_t rowA0 = (size_t)(m0 + l15) * HID + kof;
        const size_t rowA1 = (size_t)(m0 + 16 + l15) * HID + kof;
        #pragma unroll
        for (int kc = 0; kc < 128; kc += 32) {
            const int ck = kc >> 5;
            short8 a0 = *(const short8*)(Xbf + rowA0 + kc);
            short8 a1 = *(const short8*)(Xbf + rowA1 + kc);
            #pragma unroll
            for (int q = 0; q < 4; ++q) {
                int nt = q * 8 + w;
                short8 b = *(const short8*)(WswzB + (((size_t)(nt * 4 + ck)) << 9) + (l << 3));
                acc[0][q] = __builtin_amdgcn_mfma_f32_16x16x32_bf16(a0, b, acc[0][q], 0, 0, 0);
                acc[1][q] = __builtin_amdgcn_mfma_f32_16x16x32_bf16(a1, b, acc[1][q], 0, 0, 0);
            }
        }
        const float bI = bihb[j]       + bhhb[j];
        const float bG = bihb[256 + j] + bhhb[256 + j];
        const float bO = bihb[384 + j] + bhhb[384 + j];
        #pragma unroll
        for (int mt = 0; mt < 2; ++mt)
            #pragma unroll
            for (int i = 0; i < 4; ++i) {
                float gi = sigm(acc[mt][0][i] + bI);
                float gg = tanh_fast(acc[mt][2][i] + bG);
                float go = sigm(acc[mt][3][i] + bO);
                Hb[mt * 16 + quad * 4 + i][j] = f2bf(go * tanh_fast(gi * gg));
            }
    }
    __syncthreads();

    // ---- phase 2: fc1 -> F1 ----
    {
        f32x4 acc[2] = {};
        #pragma unroll
        for (int kc = 0; kc < 256; kc += 32) {
            const int ck = kc >> 5;
            short8 a0, a1;
            if (kc < 128) {
                a0 = *(const short8*)(hbf + (size_t)(m0 + l15) * HID + kc + kof);
                a1 = *(const short8*)(hbf + (size_t)(m0 + 16 + l15) * HID + kc + kof);
            } else {
                a0 = *(const short8*)(&Hb[l15][(kc - 128) + kof]);
                a1 = *(const short8*)(&Hb[16 + l15][(kc - 128) + kof]);
            }
            short8 b = *(const short8*)(WswzH + (((size_t)(w * 8 + ck)) << 9) + (l << 3));
            acc[0] = __builtin_amdgcn_mfma_f32_16x16x32_bf16(a0, b, acc[0], 0, 0, 0);
            acc[1] = __builtin_amdgcn_mfma_f32_16x16x32_bf16(a1, b, acc[1], 0, 0, 0);
        }
        const float bj = bf1[j];
        #pragma unroll
        for (int mt = 0; mt < 2; ++mt)
            #pragma unroll
            for (int i = 0; i < 4; ++i)
                F1[mt * 16 + quad * 4 + i][j] = f2bf(fmaxf(acc[mt][i] + bj, 0.f));
    }
    __syncthreads();

    // ---- phase 3: fc2 -> out ----
    {
        const int nt = w & 3, mh = w >> 2;
        f32x4 acc = {};
        #pragma unroll
        for (int kc = 0; kc < 128; kc += 32) {
            const int ck = kc >> 5;
            short8 a = *(const short8*)(&F1[mh * 16 + l15][kc + kof]);
            short8 b = *(const short8*)(WswzO + (((size_t)(nt * 4 + ck)) << 9) + (l << 3));
            acc = __builtin_amdgcn_mfma_f32_16x16x32_bf16(a, b, acc, 0, 0, 0);
        }
        const int jo = nt * 16 + l15;
        const float bj = bf2_[jo];
        const bool obf = (*oflag == 0);
        #pragma unroll
        for (int i = 0; i < 4; ++i) {
            int m = m0 + mh * 16 + quad * 4 + i;
            float o = acc[i] + bj;
            if (obf) ((u16*)out)[(size_t)m * OUT_DIM + jo] = f2bf(o);
            else     ((float*)out)[(size_t)m * OUT_DIM + jo] = o;
        }
    }
}

// ---------------------------------------------------------------------------
extern "C" void kernel_launch(void* const* d_in, const int* in_sizes, int n_in,
                              void* d_out, int out_size, void* d_ws, size_t ws_size,
                              hipStream_t stream)
{
    const void* x  = d_in[0];
    const int*  ei = (const int*)d_in[1];

    const size_t SZ_NH  = (size_t)N_NODES * HID * sizeof(float);   // 10,240,000
    const size_t SZ_NHB = (size_t)N_NODES * HID * sizeof(u16);     //  5,120,000
    const size_t SZ_I   = 80128;

    char* p = (char*)d_ws;
    float* Xa    = (float*)p; p += SZ_NH;
    float* Xb    = (float*)p; p += SZ_NH;      // leapfrog ping-pong partner
    float* scr   = (float*)p; p += SZ_NH;      // scratch (hbbf region for tail)
    float* cf    = (float*)p; p += SZ_NH;
    u16*   hbf   = (u16*)p;   p += SZ_NHB;
    u16*   XbfA  = (u16*)p;   p += SZ_NHB;
    u16*   XbfB  = (u16*)p;   p += SZ_NHB;
    int*   deg   = (int*)p;   p += SZ_I;
    int*   fill  = (int*)p;   p += SZ_I;
    int*   rowp  = (int*)p;   p += SZ_I;
    float* degf  = (float*)p; p += SZ_I;
    int*   csr   = (int*)p;   p += (size_t)N_EDGES * sizeof(int);
    int*   flag  = (int*)p;   p += 128;
    float* wsf   = (float*)p; p += 272832 * sizeof(float);
    u16*   WswzF  = (u16*)p;  p += 131072 * sizeof(u16);
    u16*   WswzB  = (u16*)p;  p += 65536 * sizeof(u16);
    u16*   WswzH  = (u16*)p;  p += 32768 * sizeof(u16);
    u16*   WswzO  = (u16*)p;  p += 8192 * sizeof(u16);
    u16*   WswzE1 = (u16*)p;  p += 16384 * sizeof(u16);
    u16*   WswzE2 = (u16*)p;  p += 16384 * sizeof(u16);

    // converted f32 weight sub-pointers (offsets match cvt_off)
    float* benc1 = wsf + 16384;
    float* benc2 = wsf + 32896;
    float* bihf  = wsf + 164096;
    float* bhhf  = wsf + 164608;
    float* bihb  = wsf + 230656;
    float* bhhb  = wsf + 231168;
    float* bf1   = wsf + 264448;
    float* bf2_  = wsf + 272768;

    hipMemsetAsync(deg, 0, 2 * SZ_I, stream);           // deg, fill (contiguous)

    // dtype detect + weight conversion (f32 master, swizzled bf16 MFMA copies)
    detect_kernel<<<1, 256, 0, stream>>>((const u16*)x, flag);
    CvtArgs ca;
    ca.s[0] = d_in[2];  ca.s[1] = d_in[3];  ca.s[2] = d_in[4];  ca.s[3] = d_in[5];
    ca.s[4] = d_in[6];  ca.s[5] = d_in[7];  ca.s[6] = d_in[8];  ca.s[7] = d_in[9];
    ca.s[8] = d_in[10]; ca.s[9] = d_in[12]; ca.s[10] = d_in[13];
    ca.s[11] = d_in[14]; ca.s[12] = d_in[15]; ca.s[13] = d_in[16]; ca.s[14] = d_in[17];
    convert_kernel<<<(272832 + 255) / 256, 256, 0, stream>>>(ca, wsf, flag);
    build_wswz_kernel<<<512, 256, 0, stream>>>(wsf, WswzF, WswzB, WswzH, WswzO,
                                               WswzE1, WswzE2);

    // CSR build
    count_kernel<<<(N_EDGES + 255) / 256, 256, 0, stream>>>(ei, deg);
    scan_kernel<<<1, 1024, 0, stream>>>(deg, rowp, degf);
    fill_kernel<<<(N_EDGES + 255) / 256, 256, 0, stream>>>(ei, rowp, fill, csr);

    const int NB = N_NODES / 32;          // 625

    // fused encoder: x -> X0 (Xa f32 + XbfA bf16), one dispatch
    encoder_kernel<<<NB, 512, 0, stream>>>(x, WswzE1, WswzE2, benc1, benc2,
                                           Xa, XbfA, flag);

    // t=0 zero-state LSTM (writes cf/hbf), then 15 x (leapfrog wave -> LSTM)
    lstm0_kernel<<<NB, 512, 0, stream>>>(XbfA, hbf, cf, WswzF, bihf, bhhf);
    u16* XbP = XbfA;
    u16* XbN = XbfB;
    float* Xc_ = Xa;   // X_{t-1}
    float* Xo_ = Xb;   // X_{t-2} -> overwritten with X_t
    for (int t = 1; t < NSTEPS; ++t) {
        if (t == 1)
            wave_kernel<true><<<N_NODES / 4, 256, 0, stream>>>(
                Xc_, Xo_, XbP, XbN, degf, rowp, csr);
        else
            wave_kernel<false><<<N_NODES / 4, 256, 0, stream>>>(
                Xc_, Xo_, XbP, XbN, degf, rowp, csr);
        float* tf = Xc_; Xc_ = Xo_; Xo_ = tf;
        u16* tmp = XbP; XbP = XbN; XbN = tmp;
        lstm_fwd_kernel<<<NB, 512, 0, stream>>>(XbP, hbf, cf, WswzF, bihf, bhhf);
    }

    // fused tail: backward cell + fc1 + fc2, one dispatch
    u16* hbbf = (u16*)scr;
    (void)hbbf;
    tail_kernel<<<NB, 512, 0, stream>>>(XbP, hbf, WswzB, WswzH, WswzO,
                                        bihb, bhhb, bf1, bf2_, d_out, flag);
}